// Round 6
// baseline (457.104 us; speedup 1.0000x reference)
//
#include <hip/hip_runtime.h>
#include <hip/hip_bf16.h>
#include <stdint.h>

// Problem constants
#define NB 32
#define NL 256
#define NS 4
#define ND 512
#define NH 1024           // NL * NS
#define FIVE_D 2560
#define HID 2048
#define MMAX 32768        // NB * NS * NL (cap on compact rows)

// Inputs: f32 / int32. OUTPUT: f32 (states [B,S,L,D] then mask [B,S,L]).
typedef __bf16 bf16_t;
typedef __bf16 bf16x4 __attribute__((ext_vector_type(4)));
typedef __bf16 bf16x8 __attribute__((ext_vector_type(8)));
typedef float f32x4 __attribute__((ext_vector_type(4)));

// async global->LDS, 16B per lane (wave-uniform base + lane*16 layout).
__device__ __forceinline__ void async_ld16(const void* g, void* l) {
  __builtin_amdgcn_global_load_lds(
      (__attribute__((address_space(1))) void*)(uintptr_t)g,
      (__attribute__((address_space(3))) void*)(uintptr_t)l, 16, 0, 0);
}

// ---------------------------------------------------------------------------
// K1: build compact row index + background fill + mask (merged fill_bg).
// ---------------------------------------------------------------------------
__global__ void build_index_kernel(const int* __restrict__ group_ids,
                                   const int* __restrict__ lengths,
                                   int* __restrict__ n_rows,
                                   int* __restrict__ row_src,
                                   int* __restrict__ row_dst,
                                   const float* __restrict__ empty_tokens,
                                   const float* __restrict__ pos_emb,
                                   const float* __restrict__ seq_emb,
                                   float* __restrict__ out,
                                   float* __restrict__ mask) {
  const int g = blockIdx.x;            // b*NS + s
  const int b = g >> 2, s = g & 3;
  const int t = threadIdx.x;           // 0..255
  const int lane = t & 63, w = t >> 6; // 4 waves
  int len = lengths[b];
  len = len < 0 ? 0 : (len > NH ? NH : len);
  const int* gi = group_ids + b * NH;

  __shared__ int wtot[16];             // per (chunk, wave) match counts
  __shared__ int sbase;

  bool valid[4];
#pragma unroll
  for (int c = 0; c < 4; ++c) {
    int h = c * 256 + t;
    valid[c] = (h < len) && (gi[h] == s + 1);
    unsigned long long m = __ballot(valid[c]);
    if (lane == 0) wtot[c * 4 + w] = __popcll(m);
  }
  __syncthreads();

  int pre[16];
  int run = 0;
#pragma unroll
  for (int i = 0; i < 16; ++i) { pre[i] = run; run += wtot[i]; }
  const int count = run;
  const int keff = count < NL ? count : NL;
  const int offset = count - keff;     // max(count - L, 0)

  if (t == 0) sbase = atomicAdd(n_rows, keff);
  __syncthreads();
  const int base = sbase;

  const unsigned long long lt = (1ull << lane) - 1ull;
#pragma unroll
  for (int c = 0; c < 4; ++c) {
    unsigned long long m = __ballot(valid[c]);
    if (valid[c]) {
      int rank = pre[c * 4 + w] + __popcll(m & lt);
      if (rank >= offset) {
        int slot = rank - offset;
        row_src[base + slot] = b * NH + c * 256 + t;
        row_dst[base + slot] = g * NL + slot;
      }
    }
  }

  // ---- merged background fill ----
  const bool empty = (count == 0);
  const int keptm = empty ? 1 : keff;
  mask[g * NL + t] = (t < keptm) ? 1.f : 0.f;      // t in [0,256)=L

  float* basep = out + (size_t)g * NL * ND;
  if (empty) {
    for (int d = t; d < ND; d += 256)
      basep[d] = empty_tokens[s * ND + d] + pos_emb[d] +
                 seq_emb[(s + 1) * ND + d];
  }
  int start = empty ? 1 : keff;
  uint4* p = (uint4*)basep;        // one slot = 128 uint4
  uint4 z; z.x = z.y = z.z = z.w = 0u;
  for (int i = start * (ND / 4) + t; i < NL * (ND / 4); i += 256) p[i] = z;
}

// ---------------------------------------------------------------------------
// K2: f32 [K,N] -> bf16 [N,K] tiled transpose (weights).
// ---------------------------------------------------------------------------
template <int KD, int NDIM>
__global__ void transpose_cvt_kernel(const float* __restrict__ src,
                                     bf16_t* __restrict__ dst) {
  __shared__ float tile[32][33];
  int k0 = blockIdx.y * 32, n0 = blockIdx.x * 32;
  int tx = threadIdx.x & 31, ty = threadIdx.x >> 5;   // 32 x 8
#pragma unroll
  for (int i = 0; i < 32; i += 8)
    tile[ty + i][tx] = src[(size_t)(k0 + ty + i) * NDIM + n0 + tx];
  __syncthreads();
#pragma unroll
  for (int i = 0; i < 32; i += 8)
    dst[(size_t)(n0 + ty + i) * KD + k0 + tx] = (bf16_t)tile[tx][ty + i];
}

// ---------------------------------------------------------------------------
// K3: gather 5 f32 embeddings + LayerNorm -> bf16 X[r_local, 2560]
// WAVE-PER-ROW (was block-per-row-stride): 4 independent waves per block,
// no LDS, no __syncthreads.  Rationale: 4 random 2KB gathers/row from a
// 102 MB table are HBM-miss-latency-bound (~900 cy); block-serial rows with
// 2 syncs/row left one row in flight per block.  Now: 10 independent float4
// loads/lane issued back-to-back, butterfly shfl_xor reduce, 8192 rows in
// flight chip-wide.  f4 idx = k*64+lane (k=0..9): seg = k>>1 for k<8, else 4
// (compile-time per unrolled k), offset = (idx&127)*4 floats.
// ---------------------------------------------------------------------------
__global__ void gather_ln_kernel(const float* __restrict__ embed,
                                 const float* __restrict__ tg_emb,
                                 const int* __restrict__ ht,
                                 const int* __restrict__ pt,
                                 const int* __restrict__ at,
                                 const int* __restrict__ ct,
                                 const int* __restrict__ tg,
                                 const float* __restrict__ gamma,
                                 const float* __restrict__ beta,
                                 const int* __restrict__ n_rows,
                                 const int* __restrict__ row_src,
                                 int row_base, int chunk,
                                 bf16_t* __restrict__ X) {
  const int t = threadIdx.x;
  const int l = t & 63;                // lane
  const int w = t >> 6;                // wave 0..3
  const int M = *n_rows;
  int lim = row_base + chunk;
  if (lim > M) lim = M;
  const int wstride = gridDim.x * 4;

  for (int r = row_base + blockIdx.x * 4 + w; r < lim; r += wstride) {
    const int rl = r - row_base;
    const int pos = row_src[r];

    const float* seg0 = embed + (size_t)ht[pos] * ND;
    const float* seg1 = embed + (size_t)pt[pos] * ND;
    const float* seg2 = embed + (size_t)at[pos] * ND;
    const float* seg3 = embed + (size_t)ct[pos] * ND;
    int tgv = tg[pos];
    tgv = tgv < 0 ? 0 : (tgv > 128 ? 128 : tgv);
    const float* seg4 = tg_emb + (size_t)tgv * ND;
    const float* segs[5] = {seg0, seg1, seg2, seg3, seg4};

    // 10 independent 16B gathers, all in flight together.
    float4 v[10];
#pragma unroll
    for (int k = 0; k < 10; ++k) {
      const int sidx = (k < 8) ? (k >> 1) : 4;       // compile-time constant
      const int idx = k * 64 + l;                    // f4 index 0..639
      v[k] = *(const float4*)(segs[sidx] + (idx & 127) * 4);
    }

    float sum = 0.f, sq = 0.f;
#pragma unroll
    for (int k = 0; k < 10; ++k) {
      sum += v[k].x + v[k].y + v[k].z + v[k].w;
      sq += v[k].x * v[k].x + v[k].y * v[k].y + v[k].z * v[k].z +
            v[k].w * v[k].w;
    }
    // 64-lane butterfly: every lane ends with the row totals.
#pragma unroll
    for (int off = 32; off > 0; off >>= 1) {
      sum += __shfl_xor(sum, off);
      sq += __shfl_xor(sq, off);
    }
    const float mu = sum * (1.f / FIVE_D);
    const float var = sq * (1.f / FIVE_D) - mu * mu;
    const float rstd = rsqrtf(var + 1e-5f);

    bf16_t* xr = X + (size_t)rl * FIVE_D;
#pragma unroll
    for (int k = 0; k < 10; ++k) {
      const int idx = k * 64 + l;
      float4 gm = *(const float4*)(gamma + idx * 4);
      float4 bt = *(const float4*)(beta + idx * 4);
      bf16x4 o;
      o[0] = (bf16_t)((v[k].x - mu) * rstd * gm.x + bt.x);
      o[1] = (bf16_t)((v[k].y - mu) * rstd * gm.y + bt.y);
      o[2] = (bf16_t)((v[k].z - mu) * rstd * gm.z + bt.z);
      o[3] = (bf16_t)((v[k].w - mu) * rstd * gm.w + bt.w);
      *(bf16x4*)(xr + idx * 4) = o;
    }
  }
}

// ---------------------------------------------------------------------------
// Shared sync macros.  v4 ledger (verified, 85.7 us @ 8k-row chunk): one
// counted wait per K-tile covering the ENTIRE previous-staged tile; A-stage
// rides ahead of the wait, B-stage issued right AFTER the wait, early in
// compute (round-3 lesson: traffic issued immediately before the wait
// competes with the loads the wait blocks on).
// vmcnt never reaches 0 in the main loop (T4); T2 swizzle + T5 setprio kept.
// ---------------------------------------------------------------------------
#define FENCE asm volatile("" ::: "memory")
#define BARRIER do { FENCE; __builtin_amdgcn_s_barrier(); FENCE; } while (0)
#define WAIT_VM(n) asm volatile("s_waitcnt vmcnt(" #n ")" ::: "memory")

// ---------------------------------------------------------------------------
// K4a: 256x256 MFMA GEMM, counted-vmcnt double-buffered schedule (plain HIP).
// C[M,N] = A[M,KD] @ Bt[N,KD]^T, epilogue bias+SiLU -> bf16 Cb.
// 512 thr = 8 waves (2M x 4N), BK=64, 128 KiB LDS double-buffer.
// ---------------------------------------------------------------------------
template <int KD, int LDC>
__launch_bounds__(512, 2)
__global__ void gemm256_kernel(const bf16_t* __restrict__ A,
                               const bf16_t* __restrict__ Bt,
                               const int* __restrict__ nrows_p,
                               int row_base,
                               const float* __restrict__ bias,
                               bf16_t* __restrict__ Cb) {
  static_assert(KD % 64 == 0 && KD / 64 >= 2, "KD");
  const int M = *nrows_p;
  const int m0 = blockIdx.y * 256;
  if (row_base + m0 >= M) return;
  const int n0 = blockIdx.x * 256;

  extern __shared__ char smem[];   // [2][ A 32KB | B 32KB ] = 128 KiB

  const int t = threadIdx.x;        // 0..511
  const int lane = t & 63;
  const int wv = t >> 6;            // 0..7
  const int wm = wv >> 2;           // 0..1  (M half)
  const int wn = wv & 3;            // 0..3  (N quarter)
  const int l15 = lane & 15;
  const int l4 = lane >> 4;

  const int r0 = t >> 3;               // 0..63 (j=1 adds 64 rows: (r&7) same)
  const int sq = (t & 7) ^ (r0 & 7);   // inverse-swizzled global chunk
  const bf16_t* Ab = A + (size_t)(m0 + r0) * KD + sq * 8;
  const bf16_t* Bb = Bt + (size_t)(n0 + r0) * KD + sq * 8;
  const int dst16 = t * 16;

  const int cs0 = (l4 ^ (l15 & 7)) << 4;   // ks=0 swizzled byte slot
  const int cs1 = cs0 ^ 64;                // ks=1
  const int arow = (wm * 128 + l15) * 128; // A row byte base for this wave
  const int brow = (wn * 64 + l15) * 128;  // B row byte base

  f32x4 acc[2][2][4][2] = {};              // [mh][nh][i][jj]
  bf16x8 a[4][2], bl[2][2], bh[2][2];

#define STAGE_A(dbuf, h, kofs)                                               \
  do {                                                                       \
    char* _d = smem + (dbuf) * 65536 + (h) * 16384 + dst16;                  \
    async_ld16(Ab + (size_t)((h) * 128) * KD + (kofs), _d);                  \
    async_ld16(Ab + (size_t)((h) * 128 + 64) * KD + (kofs), _d + 8192);      \
  } while (0)
#define STAGE_B(dbuf, h, kofs)                                               \
  do {                                                                       \
    char* _d = smem + (dbuf) * 65536 + 32768 + (h) * 16384 + dst16;          \
    async_ld16(Bb + (size_t)((h) * 128) * KD + (kofs), _d);                  \
    async_ld16(Bb + (size_t)((h) * 128 + 64) * KD + (kofs), _d + 8192);      \
  } while (0)
#define LOAD_A(cbuf, mh)                                                     \
  do {                                                                       \
    const char* _s = smem + (cbuf) * 65536 + (mh) * 8192 + arow;             \
    _Pragma("unroll") for (int _i = 0; _i < 4; ++_i) {                       \
      a[_i][0] = *(const bf16x8*)(_s + _i * 2048 + cs0);                     \
      a[_i][1] = *(const bf16x8*)(_s + _i * 2048 + cs1);                     \
    }                                                                        \
  } while (0)
#define LOAD_B(dst, cbuf, nh)                                                \
  do {                                                                       \
    const char* _s = smem + (cbuf) * 65536 + 32768 + (nh) * 4096 + brow;     \
    _Pragma("unroll") for (int _j = 0; _j < 2; ++_j) {                       \
      dst[_j][0] = *(const bf16x8*)(_s + _j * 2048 + cs0);                   \
      dst[_j][1] = *(const bf16x8*)(_s + _j * 2048 + cs1);                   \
    }                                                                        \
  } while (0)
#define MMA(mh, nh, B)                                                       \
  do {                                                                       \
    _Pragma("unroll") for (int _i = 0; _i < 4; ++_i)                         \
    _Pragma("unroll") for (int _j = 0; _j < 2; ++_j) {                       \
      acc[mh][nh][_i][_j] = __builtin_amdgcn_mfma_f32_16x16x32_bf16(         \
          a[_i][0], B[_j][0], acc[mh][nh][_i][_j], 0, 0, 0);                 \
      acc[mh][nh][_i][_j] = __builtin_amdgcn_mfma_f32_16x16x32_bf16(         \
          a[_i][1], B[_j][1], acc[mh][nh][_i][_j], 0, 0, 0);                 \
    }                                                                        \
  } while (0)

  constexpr int NT = KD / 64;

  // prologue: stage tile 0 into buf 0 (8 loads: Alo, Ahi, Blo, Bhi)
  STAGE_A(0, 0, 0);
  STAGE_A(0, 1, 0);
  STAGE_B(0, 0, 0);
  STAGE_B(0, 1, 0);

  int c = 0;
  for (int tk = 1; tk < NT; ++tk) {  // compute tile tk-1 (buf c), stage tk
    const int kn = tk * 64;
    const int d = c ^ 1;
    // stage A-halves of next tile: outstanding 8 -> 12
    STAGE_A(d, 0, kn);
    STAGE_A(d, 1, kn);
    WAIT_VM(4);      // retire exactly the previous tile's 8 loads (this wave)
    BARRIER;         // join: ALL waves' tile-c loads have landed in LDS
    // quadrant (m-lo, n-lo)
    LOAD_A(c, 0);
    LOAD_B(bl, c, 0);
    __builtin_amdgcn_s_setprio(1);
    MMA(0, 0, bl);
    __builtin_amdgcn_s_setprio(0);
    // stage B-halves of next tile EARLY in compute (after the wait, so this
    // traffic never sits ahead of a blocked wait): outstanding 4 -> 8
    STAGE_B(d, 0, kn);
    STAGE_B(d, 1, kn);
    // quadrant (m-lo, n-hi)
    LOAD_B(bh, c, 1);
    __builtin_amdgcn_s_setprio(1);
    MMA(0, 1, bh);
    __builtin_amdgcn_s_setprio(0);
    // quadrants (m-hi, n-hi) and (m-hi, n-lo)
    LOAD_A(c, 1);
    __builtin_amdgcn_s_setprio(1);
    MMA(1, 1, bh);
    MMA(1, 0, bl);
    __builtin_amdgcn_s_setprio(0);
    BARRIER;         // WAR: all reads of buf c done before tk+1 writes buf c
    c = d;
  }

  // peeled last tile: its 8 loads are the only outstanding ones
  WAIT_VM(0);
  BARRIER;
  LOAD_A(c, 0);
  LOAD_B(bl, c, 0);
  MMA(0, 0, bl);
  LOAD_B(bh, c, 1);
  MMA(0, 1, bh);
  LOAD_A(c, 1);
  MMA(1, 1, bh);
  MMA(1, 0, bl);

  // epilogue: bias + SiLU -> bf16 (rows beyond M are garbage; GEMM2 guards)
#pragma unroll
  for (int mh = 0; mh < 2; ++mh)
#pragma unroll
    for (int i = 0; i < 4; ++i) {
      const int rbase = m0 + wm * 128 + mh * 64 + i * 16 + l4 * 4;
#pragma unroll
      for (int nh = 0; nh < 2; ++nh)
#pragma unroll
        for (int j = 0; j < 2; ++j) {
          const int n = n0 + wn * 64 + nh * 32 + j * 16 + l15;
          const float bn = bias[n];
#pragma unroll
          for (int q = 0; q < 4; ++q) {
            float v = acc[mh][nh][i][j][q] + bn;
            v = v / (1.f + __expf(-v));              // SiLU
            Cb[(size_t)(rbase + q) * LDC + n] = (bf16_t)v;
          }
        }
    }
#undef STAGE_A
#undef STAGE_B
#undef LOAD_A
#undef LOAD_B
#undef MMA
}

// ---------------------------------------------------------------------------
// K4b: 128x128 MFMA GEMM for GEMM2 (N=512), same counted-vmcnt ledger.
// 512 thr = 8 waves (4M x 2N), per-wave 32x64 output, BK=64, 64 KiB LDS
// double-buffer.  Epilogue: +bias +pos_emb +seq_emb scatter via row_dst.
// ---------------------------------------------------------------------------
template <int KD>
__launch_bounds__(512, 2)
__global__ void gemm128_scatter_kernel(const bf16_t* __restrict__ A,
                                       const bf16_t* __restrict__ Bt,
                                       const int* __restrict__ nrows_p,
                                       int row_base,
                                       const float* __restrict__ bias,
                                       const int* __restrict__ row_dst,
                                       const float* __restrict__ pos_emb,
                                       const float* __restrict__ seq_emb,
                                       float* __restrict__ out) {
  static_assert(KD % 64 == 0 && KD / 64 >= 2, "KD");
  const int M = *nrows_p;
  const int m0 = blockIdx.y * 128;
  if (row_base + m0 >= M) return;
  const int n0 = blockIdx.x * 128;

  extern __shared__ char smem[];   // [2][ A 16KB | B 16KB ] = 64 KiB

  const int t = threadIdx.x;        // 0..511
  const int lane = t & 63;
  const int wv = t >> 6;            // 0..7
  const int wm = wv >> 1;           // 0..3  (M quarter, 32 rows)
  const int wn = wv & 1;            // 0..1  (N half, 64 cols)
  const int l15 = lane & 15;
  const int l4 = lane >> 4;

  const int r0 = t >> 3;               // 0..63
  const int sq = (t & 7) ^ (r0 & 7);
  const bf16_t* Ab = A + (size_t)(m0 + r0) * KD + sq * 8;
  const bf16_t* Bb = Bt + (size_t)(n0 + r0) * KD + sq * 8;
  const int dst16 = t * 16;

  const int cs0 = (l4 ^ (l15 & 7)) << 4;   // ks=0 swizzled byte slot
  const int cs1 = cs0 ^ 64;                // ks=1
  const int arow = (wm * 32 + l15) * 128;  // A row byte base for this wave
  const int brow = (wn * 64 + l15) * 128;  // B row byte base

  f32x4 acc[2][4] = {};                    // [i (16-row frag)][j (16-col frag)]
  bf16x8 a[2][2], b[4][2];

#define STAGE_A2(dbuf, kofs)                                                 \
  do {                                                                       \
    char* _d = smem + (dbuf) * 32768 + dst16;                                \
    async_ld16(Ab + (kofs), _d);                                             \
    async_ld16(Ab + (size_t)64 * KD + (kofs), _d + 8192);                    \
  } while (0)
#define STAGE_B2(dbuf, kofs)                                                 \
  do {                                                                       \
    char* _d = smem + (dbuf) * 32768 + 16384 + dst16;                        \
    async_ld16(Bb + (kofs), _d);                                             \
    async_ld16(Bb + (size_t)64 * KD + (kofs), _d + 8192);                    \
  } while (0)
#define LOAD_A2(cbuf)                                                        \
  do {                                                                       \
    const char* _s = smem + (cbuf) * 32768 + arow;                           \
    _Pragma("unroll") for (int _i = 0; _i < 2; ++_i) {                       \
      a[_i][0] = *(const bf16x8*)(_s + _i * 2048 + cs0);                     \
      a[_i][1] = *(const bf16x8*)(_s + _i * 2048 + cs1);                     \
    }                                                                        \
  } while (0)
#define LOAD_B2(cbuf)                                                        \
  do {                                                                       \
    const char* _s = smem + (cbuf) * 32768 + 16384 + brow;                   \
    _Pragma("unroll") for (int _j = 0; _j < 4; ++_j) {                       \
      b[_j][0] = *(const bf16x8*)(_s + _j * 2048 + cs0);                     \
      b[_j][1] = *(const bf16x8*)(_s + _j * 2048 + cs1);                     \
    }                                                                        \
  } while (0)
#define MMA2                                                                 \
  do {                                                                       \
    _Pragma("unroll") for (int _i = 0; _i < 2; ++_i)                         \
    _Pragma("unroll") for (int _j = 0; _j < 4; ++_j) {                       \
      acc[_i][_j] = __builtin_amdgcn_mfma_f32_16x16x32_bf16(                 \
          a[_i][0], b[_j][0], acc[_i][_j], 0, 0, 0);                         \
      acc[_i][_j] = __builtin_amdgcn_mfma_f32_16x16x32_bf16(                 \
          a[_i][1], b[_j][1], acc[_i][_j], 0, 0, 0);                         \
    }                                                                        \
  } while (0)

  constexpr int NT = KD / 64;

  // prologue: stage tile 0 (4 loads)
  STAGE_A2(0, 0);
  STAGE_B2(0, 0);

  int c = 0;
  for (int tk = 1; tk < NT; ++tk) {
    const int kn = tk * 64;
    const int d = c ^ 1;
    STAGE_A2(d, kn);            // outstanding 4 -> 6
    WAIT_VM(2);                 // retire exactly the previous tile's 4 loads
    BARRIER;
    LOAD_A2(c);
    LOAD_B2(c);
    STAGE_B2(d, kn);            // issue B after the wait: 2 -> 4
    __builtin_amdgcn_s_setprio(1);
    MMA2;
    __builtin_amdgcn_s_setprio(0);
    BARRIER;                    // WAR before next iter writes buf c
    c = d;
  }

  WAIT_VM(0);
  BARRIER;
  LOAD_A2(c);
  LOAD_B2(c);
  MMA2;

  // epilogue: scatter rows via row_dst, +bias +pos_emb +seq_emb (f32 out)
#pragma unroll
  for (int i = 0; i < 2; ++i) {
    int mbase = m0 + wm * 32 + i * 16 + l4 * 4;     // local row
#pragma unroll
    for (int q = 0; q < 4; ++q) {
      int r = mbase + q;                            // local row
      if (row_base + r >= M) continue;
      int dst = row_dst[row_base + r];              // (b*S+s)*L + slot
      int slot = dst & (NL - 1);
      int sg = (dst >> 8) & 3;
#pragma unroll
      for (int j = 0; j < 4; ++j) {
        int n = n0 + wn * 64 + j * 16 + l15;
        float v = acc[i][j][q] + bias[n] + pos_emb[slot * ND + n] +
                  seq_emb[(sg + 1) * ND + n];
        out[(size_t)dst * ND + n] = v;              // f32 output
      }
    }
  }
#undef STAGE_A2
#undef STAGE_B2
#undef LOAD_A2
#undef LOAD_B2
#undef MMA2
}

// ---------------------------------------------------------------------------
extern "C" void kernel_launch(void* const* d_in, const int* in_sizes, int n_in,
                              void* d_out, int out_size, void* d_ws,
                              size_t ws_size, hipStream_t stream) {
  const float* embed_table = (const float*)d_in[0];
  const float* time_gap_emb = (const float*)d_in[1];
  const float* seq_id_emb = (const float*)d_in[2];
  const float* pos_emb = (const float*)d_in[3];
  const float* ln_gamma = (const float*)d_in[4];
  const float* ln_beta = (const float*)d_in[5];
  const float* w1 = (const float*)d_in[6];
  const float* b1 = (const float*)d_in[7];
  const float* w2 = (const float*)d_in[8];
  const float* b2 = (const float*)d_in[9];
  const float* empty_tokens = (const float*)d_in[10];
  const int* history_tokens = (const int*)d_in[11];
  const int* post_tokens = (const int*)d_in[12];
  const int* author_tokens = (const int*)d_in[13];
  const int* action_tokens = (const int*)d_in[14];
  const int* time_gap = (const int*)d_in[15];
  const int* group_ids = (const int*)d_in[16];
  const int* lengths = (const int*)d_in[17];

  // Runtime-adaptive chunking.  ws_size is constant across calls/replays, so
  // this branch is identical on every invocation (graph-capture safe).
  const size_t fixed = 266240 + (size_t)(HID * FIVE_D + ND * HID) * 2;
  int chunk, nchunk;
  if (ws_size >= fixed + (size_t)32768 * 9216) { chunk = 32768; nchunk = 1; }
  else if (ws_size >= fixed + (size_t)16384 * 9216) { chunk = 16384; nchunk = 2; }
  else { chunk = 8192; nchunk = 4; }

  char* ws = (char*)d_ws;
  int* n_rows = (int*)ws;                                  // 4 B
  int* row_src = (int*)(ws + 4096);                        // 32768*4 B
  int* row_dst = (int*)(ws + 4096 + 131072);               // 32768*4 B
  bf16_t* W1T = (bf16_t*)(ws + 266240);                    // [2048][2560] bf16
  bf16_t* W2T = W1T + (size_t)HID * FIVE_D;                // [512][2048]  bf16
  bf16_t* Xc = W2T + (size_t)ND * HID;                     // [chunk][2560] bf16
  bf16_t* H1c = Xc + (size_t)chunk * FIVE_D;               // [chunk][2048] bf16

  float* out_states = (float*)d_out;                       // f32 output
  float* out_mask = out_states + (size_t)NB * NS * NL * ND;

  // Dynamic-LDS opt-in for the two GEMMs (host-side, idempotent).
  (void)hipFuncSetAttribute(
      reinterpret_cast<const void*>(gemm256_kernel<FIVE_D, HID>),
      hipFuncAttributeMaxDynamicSharedMemorySize, 131072);
  (void)hipFuncSetAttribute(
      reinterpret_cast<const void*>(gemm128_scatter_kernel<HID>),
      hipFuncAttributeMaxDynamicSharedMemorySize, 65536);

  // n_rows must start at 0 (ws is poisoned 0xAA before every launch).
  hipMemsetAsync(n_rows, 0, 4, stream);

  build_index_kernel<<<NB * NS, 256, 0, stream>>>(
      group_ids, lengths, n_rows, row_src, row_dst, empty_tokens, pos_emb,
      seq_id_emb, out_states, out_mask);

  transpose_cvt_kernel<FIVE_D, HID>
      <<<dim3(HID / 32, FIVE_D / 32), 256, 0, stream>>>(w1, W1T);
  transpose_cvt_kernel<HID, ND>
      <<<dim3(ND / 32, HID / 32), 256, 0, stream>>>(w2, W2T);

  for (int c = 0; c < nchunk; ++c) {
    int row_base = c * chunk;
    gather_ln_kernel<<<2048, 256, 0, stream>>>(
        embed_table, time_gap_emb, history_tokens, post_tokens, author_tokens,
        action_tokens, time_gap, ln_gamma, ln_beta, n_rows, row_src, row_base,
        chunk, Xc);

    gemm256_kernel<FIVE_D, HID>
        <<<dim3(HID / 256, chunk / 256), 512, 131072, stream>>>(
            Xc, W1T, n_rows, row_base, b1, H1c);

    gemm128_scatter_kernel<HID>
        <<<dim3(ND / 128, chunk / 128), 512, 65536, stream>>>(
            H1c, W2T, n_rows, row_base, b2, row_dst, pos_emb, seq_id_emb,
            out_states);
  }
}

// Round 7
// 410.084 us; speedup vs baseline: 1.1147x; 1.1147x over previous
//
#include <hip/hip_runtime.h>
#include <hip/hip_bf16.h>
#include <stdint.h>

// Problem constants
#define NB 32
#define NL 256
#define NS 4
#define ND 512
#define NH 1024           // NL * NS
#define FIVE_D 2560
#define HID 2048
#define MMAX 32768        // NB * NS * NL (cap on compact rows)

// Inputs: f32 / int32. OUTPUT: f32 (states [B,S,L,D] then mask [B,S,L]).
typedef __bf16 bf16_t;
typedef __bf16 bf16x4 __attribute__((ext_vector_type(4)));
typedef __bf16 bf16x8 __attribute__((ext_vector_type(8)));
typedef float f32x4 __attribute__((ext_vector_type(4)));

// async global->LDS, 16B per lane (wave-uniform base + lane*16 layout).
__device__ __forceinline__ void async_ld16(const void* g, void* l) {
  __builtin_amdgcn_global_load_lds(
      (__attribute__((address_space(1))) void*)(uintptr_t)g,
      (__attribute__((address_space(3))) void*)(uintptr_t)l, 16, 0, 0);
}

// ---------------------------------------------------------------------------
// K1: build compact row index + background fill + mask (merged fill_bg).
// ---------------------------------------------------------------------------
__global__ void build_index_kernel(const int* __restrict__ group_ids,
                                   const int* __restrict__ lengths,
                                   int* __restrict__ n_rows,
                                   int* __restrict__ row_src,
                                   int* __restrict__ row_dst,
                                   const float* __restrict__ empty_tokens,
                                   const float* __restrict__ pos_emb,
                                   const float* __restrict__ seq_emb,
                                   float* __restrict__ out,
                                   float* __restrict__ mask) {
  const int g = blockIdx.x;            // b*NS + s
  const int b = g >> 2, s = g & 3;
  const int t = threadIdx.x;           // 0..255
  const int lane = t & 63, w = t >> 6; // 4 waves
  int len = lengths[b];
  len = len < 0 ? 0 : (len > NH ? NH : len);
  const int* gi = group_ids + b * NH;

  __shared__ int wtot[16];             // per (chunk, wave) match counts
  __shared__ int sbase;

  bool valid[4];
#pragma unroll
  for (int c = 0; c < 4; ++c) {
    int h = c * 256 + t;
    valid[c] = (h < len) && (gi[h] == s + 1);
    unsigned long long m = __ballot(valid[c]);
    if (lane == 0) wtot[c * 4 + w] = __popcll(m);
  }
  __syncthreads();

  int pre[16];
  int run = 0;
#pragma unroll
  for (int i = 0; i < 16; ++i) { pre[i] = run; run += wtot[i]; }
  const int count = run;
  const int keff = count < NL ? count : NL;
  const int offset = count - keff;     // max(count - L, 0)

  if (t == 0) sbase = atomicAdd(n_rows, keff);
  __syncthreads();
  const int base = sbase;

  const unsigned long long lt = (1ull << lane) - 1ull;
#pragma unroll
  for (int c = 0; c < 4; ++c) {
    unsigned long long m = __ballot(valid[c]);
    if (valid[c]) {
      int rank = pre[c * 4 + w] + __popcll(m & lt);
      if (rank >= offset) {
        int slot = rank - offset;
        row_src[base + slot] = b * NH + c * 256 + t;
        row_dst[base + slot] = g * NL + slot;
      }
    }
  }

  // ---- merged background fill ----
  const bool empty = (count == 0);
  const int keptm = empty ? 1 : keff;
  mask[g * NL + t] = (t < keptm) ? 1.f : 0.f;      // t in [0,256)=L

  float* basep = out + (size_t)g * NL * ND;
  if (empty) {
    for (int d = t; d < ND; d += 256)
      basep[d] = empty_tokens[s * ND + d] + pos_emb[d] +
                 seq_emb[(s + 1) * ND + d];
  }
  int start = empty ? 1 : keff;
  uint4* p = (uint4*)basep;        // one slot = 128 uint4
  uint4 z; z.x = z.y = z.z = z.w = 0u;
  for (int i = start * (ND / 4) + t; i < NL * (ND / 4); i += 256) p[i] = z;
}

// ---------------------------------------------------------------------------
// K2: f32 [K,N] -> bf16 [N,K] tiled transpose (weights).
// ---------------------------------------------------------------------------
template <int KD, int NDIM>
__global__ void transpose_cvt_kernel(const float* __restrict__ src,
                                     bf16_t* __restrict__ dst) {
  __shared__ float tile[32][33];
  int k0 = blockIdx.y * 32, n0 = blockIdx.x * 32;
  int tx = threadIdx.x & 31, ty = threadIdx.x >> 5;   // 32 x 8
#pragma unroll
  for (int i = 0; i < 32; i += 8)
    tile[ty + i][tx] = src[(size_t)(k0 + ty + i) * NDIM + n0 + tx];
  __syncthreads();
#pragma unroll
  for (int i = 0; i < 32; i += 8)
    dst[(size_t)(n0 + ty + i) * KD + k0 + tx] = (bf16_t)tile[tx][ty + i];
}

// ---------------------------------------------------------------------------
// K3: gather 5 f32 embeddings + LayerNorm -> bf16 X[r_local, 2560]
// Block-per-row (the verified r5 structure) with three fixes, every index
// compile-time static BY CONSTRUCTION (round-6 lesson, rule #20: any
// runtime-indexed local array demotes to scratch — the +40us regression):
//  * 128 threads/block, 5 NAMED float4 loads v0..v4: element idx = k*512+t*4,
//    so segment = k exactly (static), offset = t*16B — each segment is one
//    fully-coalesced 2KB sweep.
//  * ONE sync per row (was 2) via parity-double-buffered LDS reduce slots.
//    (reads of slot p in iter i finish before sync_{i+1}; the next write of
//    slot p is in iter i+2, after sync_{i+1} — safe.)
//  * 4096 blocks x 2 waves = 32 waves/CU: whole grid co-resident, ~4096 rows
//    in flight (2x round-5).
// ---------------------------------------------------------------------------
__launch_bounds__(128)
__global__ void gather_ln_kernel(const float* __restrict__ embed,
                                 const float* __restrict__ tg_emb,
                                 const int* __restrict__ ht,
                                 const int* __restrict__ pt,
                                 const int* __restrict__ at,
                                 const int* __restrict__ ct,
                                 const int* __restrict__ tg,
                                 const float* __restrict__ gamma,
                                 const float* __restrict__ beta,
                                 const int* __restrict__ n_rows,
                                 const int* __restrict__ row_src,
                                 int row_base, int chunk,
                                 bf16_t* __restrict__ X) {
  const int t = threadIdx.x;           // 0..127
  const int w = t >> 6;                // wave 0..1
  const int M = *n_rows;
  int lim = row_base + chunk;
  if (lim > M) lim = M;

  __shared__ float red2[2][4];         // [parity][sum0,sum1,sq0,sq1]
  int par = 0;

  // static per-thread offsets (16B per thread per segment)
  const int o = t * 4;                 // float offset within a 512-float seg

  for (int r = row_base + blockIdx.x; r < lim; r += gridDim.x) {
    const int rl = r - row_base;
    const int pos = row_src[r];

    const float* s0 = embed + (size_t)ht[pos] * ND;
    const float* s1 = embed + (size_t)pt[pos] * ND;
    const float* s2 = embed + (size_t)at[pos] * ND;
    const float* s3 = embed + (size_t)ct[pos] * ND;
    int tgv = tg[pos];
    tgv = tgv < 0 ? 0 : (tgv > 128 ? 128 : tgv);
    const float* s4 = tg_emb + (size_t)tgv * ND;

    // 5 independent 16B loads, all named (registers by construction).
    float4 v0 = *(const float4*)(s0 + o);
    float4 v1 = *(const float4*)(s1 + o);
    float4 v2 = *(const float4*)(s2 + o);
    float4 v3 = *(const float4*)(s3 + o);
    float4 v4 = *(const float4*)(s4 + o);

    float sum = v0.x + v0.y + v0.z + v0.w + v1.x + v1.y + v1.z + v1.w +
                v2.x + v2.y + v2.z + v2.w + v3.x + v3.y + v3.z + v3.w +
                v4.x + v4.y + v4.z + v4.w;
    float sq = v0.x * v0.x + v0.y * v0.y + v0.z * v0.z + v0.w * v0.w +
               v1.x * v1.x + v1.y * v1.y + v1.z * v1.z + v1.w * v1.w +
               v2.x * v2.x + v2.y * v2.y + v2.z * v2.z + v2.w * v2.w +
               v3.x * v3.x + v3.y * v3.y + v3.z * v3.z + v3.w * v3.w +
               v4.x * v4.x + v4.y * v4.y + v4.z * v4.z + v4.w * v4.w;
#pragma unroll
    for (int off = 32; off > 0; off >>= 1) {
      sum += __shfl_xor(sum, off);
      sq += __shfl_xor(sq, off);
    }
    if ((t & 63) == 0) { red2[par][w] = sum; red2[par][2 + w] = sq; }
    __syncthreads();                   // the ONLY sync per row
    const float S = red2[par][0] + red2[par][1];
    const float Q = red2[par][2] + red2[par][3];
    par ^= 1;
    const float mu = S * (1.f / FIVE_D);
    const float var = Q * (1.f / FIVE_D) - mu * mu;
    const float rstd = rsqrtf(var + 1e-5f);

    bf16_t* xr = X + (size_t)rl * FIVE_D;
#define LN_STORE(vk, kk)                                                     \
    do {                                                                     \
      float4 gm = *(const float4*)(gamma + (kk)*512 + o);                    \
      float4 bt = *(const float4*)(beta + (kk)*512 + o);                     \
      bf16x4 ov;                                                             \
      ov[0] = (bf16_t)((vk.x - mu) * rstd * gm.x + bt.x);                    \
      ov[1] = (bf16_t)((vk.y - mu) * rstd * gm.y + bt.y);                    \
      ov[2] = (bf16_t)((vk.z - mu) * rstd * gm.z + bt.z);                    \
      ov[3] = (bf16_t)((vk.w - mu) * rstd * gm.w + bt.w);                    \
      *(bf16x4*)(xr + (kk)*512 + o) = ov;                                    \
    } while (0)
    LN_STORE(v0, 0);
    LN_STORE(v1, 1);
    LN_STORE(v2, 2);
    LN_STORE(v3, 3);
    LN_STORE(v4, 4);
#undef LN_STORE
  }
}

// ---------------------------------------------------------------------------
// Shared sync macros.  v4 ledger (verified): one counted wait per K-tile
// covering the ENTIRE previous-staged tile; A-stage rides ahead of the wait,
// B-stage issued right AFTER the wait, early in compute (round-3 lesson:
// traffic issued immediately before the wait competes with the loads the
// wait blocks on).  vmcnt never reaches 0 in the main loop (T4); T2 swizzle
// + T5 setprio kept.  No explicit lgkmcnt drains (compiler-visible ds_reads).
// ---------------------------------------------------------------------------
#define FENCE asm volatile("" ::: "memory")
#define BARRIER do { FENCE; __builtin_amdgcn_s_barrier(); FENCE; } while (0)
#define WAIT_VM(n) asm volatile("s_waitcnt vmcnt(" #n ")" ::: "memory")

// ---------------------------------------------------------------------------
// K4a: 256x256 MFMA GEMM, counted-vmcnt double-buffered schedule (plain HIP).
// C[M,N] = A[M,KD] @ Bt[N,KD]^T, epilogue bias+SiLU -> bf16 Cb.
// 512 thr = 8 waves (2M x 4N), BK=64, 128 KiB LDS double-buffer.
// ---------------------------------------------------------------------------
template <int KD, int LDC>
__launch_bounds__(512, 2)
__global__ void gemm256_kernel(const bf16_t* __restrict__ A,
                               const bf16_t* __restrict__ Bt,
                               const int* __restrict__ nrows_p,
                               int row_base,
                               const float* __restrict__ bias,
                               bf16_t* __restrict__ Cb) {
  static_assert(KD % 64 == 0 && KD / 64 >= 2, "KD");
  const int M = *nrows_p;
  const int m0 = blockIdx.y * 256;
  if (row_base + m0 >= M) return;
  const int n0 = blockIdx.x * 256;

  extern __shared__ char smem[];   // [2][ A 32KB | B 32KB ] = 128 KiB

  const int t = threadIdx.x;        // 0..511
  const int lane = t & 63;
  const int wv = t >> 6;            // 0..7
  const int wm = wv >> 2;           // 0..1  (M half)
  const int wn = wv & 3;            // 0..3  (N quarter)
  const int l15 = lane & 15;
  const int l4 = lane >> 4;

  const int r0 = t >> 3;               // 0..63 (j=1 adds 64 rows: (r&7) same)
  const int sq = (t & 7) ^ (r0 & 7);   // inverse-swizzled global chunk
  const bf16_t* Ab = A + (size_t)(m0 + r0) * KD + sq * 8;
  const bf16_t* Bb = Bt + (size_t)(n0 + r0) * KD + sq * 8;
  const int dst16 = t * 16;

  const int cs0 = (l4 ^ (l15 & 7)) << 4;   // ks=0 swizzled byte slot
  const int cs1 = cs0 ^ 64;                // ks=1
  const int arow = (wm * 128 + l15) * 128; // A row byte base for this wave
  const int brow = (wn * 64 + l15) * 128;  // B row byte base

  f32x4 acc[2][2][4][2] = {};              // [mh][nh][i][jj]
  bf16x8 a[4][2], bl[2][2], bh[2][2];

#define STAGE_A(dbuf, h, kofs)                                               \
  do {                                                                       \
    char* _d = smem + (dbuf) * 65536 + (h) * 16384 + dst16;                  \
    async_ld16(Ab + (size_t)((h) * 128) * KD + (kofs), _d);                  \
    async_ld16(Ab + (size_t)((h) * 128 + 64) * KD + (kofs), _d + 8192);      \
  } while (0)
#define STAGE_B(dbuf, h, kofs)                                               \
  do {                                                                       \
    char* _d = smem + (dbuf) * 65536 + 32768 + (h) * 16384 + dst16;          \
    async_ld16(Bb + (size_t)((h) * 128) * KD + (kofs), _d);                  \
    async_ld16(Bb + (size_t)((h) * 128 + 64) * KD + (kofs), _d + 8192);      \
  } while (0)
#define LOAD_A(cbuf, mh)                                                     \
  do {                                                                       \
    const char* _s = smem + (cbuf) * 65536 + (mh) * 8192 + arow;             \
    _Pragma("unroll") for (int _i = 0; _i < 4; ++_i) {                       \
      a[_i][0] = *(const bf16x8*)(_s + _i * 2048 + cs0);                     \
      a[_i][1] = *(const bf16x8*)(_s + _i * 2048 + cs1);                     \
    }                                                                        \
  } while (0)
#define LOAD_B(dst, cbuf, nh)                                                \
  do {                                                                       \
    const char* _s = smem + (cbuf) * 65536 + 32768 + (nh) * 4096 + brow;     \
    _Pragma("unroll") for (int _j = 0; _j < 2; ++_j) {                       \
      dst[_j][0] = *(const bf16x8*)(_s + _j * 2048 + cs0);                   \
      dst[_j][1] = *(const bf16x8*)(_s + _j * 2048 + cs1);                   \
    }                                                                        \
  } while (0)
#define MMA(mh, nh, B)                                                       \
  do {                                                                       \
    _Pragma("unroll") for (int _i = 0; _i < 4; ++_i)                         \
    _Pragma("unroll") for (int _j = 0; _j < 2; ++_j) {                       \
      acc[mh][nh][_i][_j] = __builtin_amdgcn_mfma_f32_16x16x32_bf16(         \
          a[_i][0], B[_j][0], acc[mh][nh][_i][_j], 0, 0, 0);                 \
      acc[mh][nh][_i][_j] = __builtin_amdgcn_mfma_f32_16x16x32_bf16(         \
          a[_i][1], B[_j][1], acc[mh][nh][_i][_j], 0, 0, 0);                 \
    }                                                                        \
  } while (0)

  constexpr int NT = KD / 64;

  // prologue: stage tile 0 into buf 0 (8 loads: Alo, Ahi, Blo, Bhi)
  STAGE_A(0, 0, 0);
  STAGE_A(0, 1, 0);
  STAGE_B(0, 0, 0);
  STAGE_B(0, 1, 0);

  int c = 0;
  for (int tk = 1; tk < NT; ++tk) {  // compute tile tk-1 (buf c), stage tk
    const int kn = tk * 64;
    const int d = c ^ 1;
    // stage A-halves of next tile: outstanding 8 -> 12
    STAGE_A(d, 0, kn);
    STAGE_A(d, 1, kn);
    WAIT_VM(4);      // retire exactly the previous tile's 8 loads (this wave)
    BARRIER;         // join: ALL waves' tile-c loads have landed in LDS
    // quadrant (m-lo, n-lo)
    LOAD_A(c, 0);
    LOAD_B(bl, c, 0);
    __builtin_amdgcn_s_setprio(1);
    MMA(0, 0, bl);
    __builtin_amdgcn_s_setprio(0);
    // stage B-halves of next tile EARLY in compute (after the wait, so this
    // traffic never sits ahead of a blocked wait): outstanding 4 -> 8
    STAGE_B(d, 0, kn);
    STAGE_B(d, 1, kn);
    // quadrant (m-lo, n-hi)
    LOAD_B(bh, c, 1);
    __builtin_amdgcn_s_setprio(1);
    MMA(0, 1, bh);
    __builtin_amdgcn_s_setprio(0);
    // quadrants (m-hi, n-hi) and (m-hi, n-lo)
    LOAD_A(c, 1);
    __builtin_amdgcn_s_setprio(1);
    MMA(1, 1, bh);
    MMA(1, 0, bl);
    __builtin_amdgcn_s_setprio(0);
    BARRIER;         // WAR: all reads of buf c done before tk+1 writes buf c
    c = d;
  }

  // peeled last tile: its 8 loads are the only outstanding ones
  WAIT_VM(0);
  BARRIER;
  LOAD_A(c, 0);
  LOAD_B(bl, c, 0);
  MMA(0, 0, bl);
  LOAD_B(bh, c, 1);
  MMA(0, 1, bh);
  LOAD_A(c, 1);
  MMA(1, 1, bh);
  MMA(1, 0, bl);

  // epilogue: bias + SiLU -> bf16 (rows beyond M are garbage; GEMM2 guards)
#pragma unroll
  for (int mh = 0; mh < 2; ++mh)
#pragma unroll
    for (int i = 0; i < 4; ++i) {
      const int rbase = m0 + wm * 128 + mh * 64 + i * 16 + l4 * 4;
#pragma unroll
      for (int nh = 0; nh < 2; ++nh)
#pragma unroll
        for (int j = 0; j < 2; ++j) {
          const int n = n0 + wn * 64 + nh * 32 + j * 16 + l15;
          const float bn = bias[n];
#pragma unroll
          for (int q = 0; q < 4; ++q) {
            float v = acc[mh][nh][i][j][q] + bn;
            v = v / (1.f + __expf(-v));              // SiLU
            Cb[(size_t)(rbase + q) * LDC + n] = (bf16_t)v;
          }
        }
    }
#undef STAGE_A
#undef STAGE_B
#undef LOAD_A
#undef LOAD_B
#undef MMA
}

// ---------------------------------------------------------------------------
// K4b: 128x128 MFMA GEMM for GEMM2 (N=512), same counted-vmcnt ledger.
// 512 thr = 8 waves (4M x 2N), per-wave 32x64 output, BK=64, 64 KiB LDS
// double-buffer.  Epilogue: +bias +pos_emb +seq_emb scatter via row_dst.
// ---------------------------------------------------------------------------
template <int KD>
__launch_bounds__(512, 2)
__global__ void gemm128_scatter_kernel(const bf16_t* __restrict__ A,
                                       const bf16_t* __restrict__ Bt,
                                       const int* __restrict__ nrows_p,
                                       int row_base,
                                       const float* __restrict__ bias,
                                       const int* __restrict__ row_dst,
                                       const float* __restrict__ pos_emb,
                                       const float* __restrict__ seq_emb,
                                       float* __restrict__ out) {
  static_assert(KD % 64 == 0 && KD / 64 >= 2, "KD");
  const int M = *nrows_p;
  const int m0 = blockIdx.y * 128;
  if (row_base + m0 >= M) return;
  const int n0 = blockIdx.x * 128;

  extern __shared__ char smem[];   // [2][ A 16KB | B 16KB ] = 64 KiB

  const int t = threadIdx.x;        // 0..511
  const int lane = t & 63;
  const int wv = t >> 6;            // 0..7
  const int wm = wv >> 1;           // 0..3  (M quarter, 32 rows)
  const int wn = wv & 1;            // 0..1  (N half, 64 cols)
  const int l15 = lane & 15;
  const int l4 = lane >> 4;

  const int r0 = t >> 3;               // 0..63
  const int sq = (t & 7) ^ (r0 & 7);
  const bf16_t* Ab = A + (size_t)(m0 + r0) * KD + sq * 8;
  const bf16_t* Bb = Bt + (size_t)(n0 + r0) * KD + sq * 8;
  const int dst16 = t * 16;

  const int cs0 = (l4 ^ (l15 & 7)) << 4;   // ks=0 swizzled byte slot
  const int cs1 = cs0 ^ 64;                // ks=1
  const int arow = (wm * 32 + l15) * 128;  // A row byte base for this wave
  const int brow = (wn * 64 + l15) * 128;  // B row byte base

  f32x4 acc[2][4] = {};                    // [i (16-row frag)][j (16-col frag)]
  bf16x8 a[2][2], b[4][2];

#define STAGE_A2(dbuf, kofs)                                                 \
  do {                                                                       \
    char* _d = smem + (dbuf) * 32768 + dst16;                                \
    async_ld16(Ab + (kofs), _d);                                             \
    async_ld16(Ab + (size_t)64 * KD + (kofs), _d + 8192);                    \
  } while (0)
#define STAGE_B2(dbuf, kofs)                                                 \
  do {                                                                       \
    char* _d = smem + (dbuf) * 32768 + 16384 + dst16;                        \
    async_ld16(Bb + (kofs), _d);                                             \
    async_ld16(Bb + (size_t)64 * KD + (kofs), _d + 8192);                    \
  } while (0)
#define LOAD_A2(cbuf)                                                        \
  do {                                                                       \
    const char* _s = smem + (cbuf) * 32768 + arow;                           \
    _Pragma("unroll") for (int _i = 0; _i < 2; ++_i) {                       \
      a[_i][0] = *(const bf16x8*)(_s + _i * 2048 + cs0);                     \
      a[_i][1] = *(const bf16x8*)(_s + _i * 2048 + cs1);                     \
    }                                                                        \
  } while (0)
#define LOAD_B2(cbuf)                                                        \
  do {                                                                       \
    const char* _s = smem + (cbuf) * 32768 + 16384 + brow;                   \
    _Pragma("unroll") for (int _j = 0; _j < 4; ++_j) {                       \
      b[_j][0] = *(const bf16x8*)(_s + _j * 2048 + cs0);                     \
      b[_j][1] = *(const bf16x8*)(_s + _j * 2048 + cs1);                     \
    }                                                                        \
  } while (0)
#define MMA2                                                                 \
  do {                                                                       \
    _Pragma("unroll") for (int _i = 0; _i < 2; ++_i)                         \
    _Pragma("unroll") for (int _j = 0; _j < 4; ++_j) {                       \
      acc[_i][_j] = __builtin_amdgcn_mfma_f32_16x16x32_bf16(                 \
          a[_i][0], b[_j][0], acc[_i][_j], 0, 0, 0);                         \
      acc[_i][_j] = __builtin_amdgcn_mfma_f32_16x16x32_bf16(                 \
          a[_i][1], b[_j][1], acc[_i][_j], 0, 0, 0);                         \
    }                                                                        \
  } while (0)

  constexpr int NT = KD / 64;

  // prologue: stage tile 0 (4 loads)
  STAGE_A2(0, 0);
  STAGE_B2(0, 0);

  int c = 0;
  for (int tk = 1; tk < NT; ++tk) {
    const int kn = tk * 64;
    const int d = c ^ 1;
    STAGE_A2(d, kn);            // outstanding 4 -> 6
    WAIT_VM(2);                 // retire exactly the previous tile's 4 loads
    BARRIER;
    LOAD_A2(c);
    LOAD_B2(c);
    STAGE_B2(d, kn);            // issue B after the wait: 2 -> 4
    __builtin_amdgcn_s_setprio(1);
    MMA2;
    __builtin_amdgcn_s_setprio(0);
    BARRIER;                    // WAR before next iter writes buf c
    c = d;
  }

  WAIT_VM(0);
  BARRIER;
  LOAD_A2(c);
  LOAD_B2(c);
  MMA2;

  // epilogue: scatter rows via row_dst, +bias +pos_emb +seq_emb (f32 out)
#pragma unroll
  for (int i = 0; i < 2; ++i) {
    int mbase = m0 + wm * 32 + i * 16 + l4 * 4;     // local row
#pragma unroll
    for (int q = 0; q < 4; ++q) {
      int r = mbase + q;                            // local row
      if (row_base + r >= M) continue;
      int dst = row_dst[row_base + r];              // (b*S+s)*L + slot
      int slot = dst & (NL - 1);
      int sg = (dst >> 8) & 3;
#pragma unroll
      for (int j = 0; j < 4; ++j) {
        int n = n0 + wn * 64 + j * 16 + l15;
        float v = acc[i][j][q] + bias[n] + pos_emb[slot * ND + n] +
                  seq_emb[(sg + 1) * ND + n];
        out[(size_t)dst * ND + n] = v;              // f32 output
      }
    }
  }
#undef STAGE_A2
#undef STAGE_B2
#undef LOAD_A2
#undef LOAD_B2
#undef MMA2
}

// ---------------------------------------------------------------------------
extern "C" void kernel_launch(void* const* d_in, const int* in_sizes, int n_in,
                              void* d_out, int out_size, void* d_ws,
                              size_t ws_size, hipStream_t stream) {
  const float* embed_table = (const float*)d_in[0];
  const float* time_gap_emb = (const float*)d_in[1];
  const float* seq_id_emb = (const float*)d_in[2];
  const float* pos_emb = (const float*)d_in[3];
  const float* ln_gamma = (const float*)d_in[4];
  const float* ln_beta = (const float*)d_in[5];
  const float* w1 = (const float*)d_in[6];
  const float* b1 = (const float*)d_in[7];
  const float* w2 = (const float*)d_in[8];
  const float* b2 = (const float*)d_in[9];
  const float* empty_tokens = (const float*)d_in[10];
  const int* history_tokens = (const int*)d_in[11];
  const int* post_tokens = (const int*)d_in[12];
  const int* author_tokens = (const int*)d_in[13];
  const int* action_tokens = (const int*)d_in[14];
  const int* time_gap = (const int*)d_in[15];
  const int* group_ids = (const int*)d_in[16];
  const int* lengths = (const int*)d_in[17];

  // Runtime-adaptive chunking.  ws_size is constant across calls/replays, so
  // this branch is identical on every invocation (graph-capture safe).
  const size_t fixed = 266240 + (size_t)(HID * FIVE_D + ND * HID) * 2;
  int chunk, nchunk;
  if (ws_size >= fixed + (size_t)32768 * 9216) { chunk = 32768; nchunk = 1; }
  else if (ws_size >= fixed + (size_t)16384 * 9216) { chunk = 16384; nchunk = 2; }
  else { chunk = 8192; nchunk = 4; }

  char* ws = (char*)d_ws;
  int* n_rows = (int*)ws;                                  // 4 B
  int* row_src = (int*)(ws + 4096);                        // 32768*4 B
  int* row_dst = (int*)(ws + 4096 + 131072);               // 32768*4 B
  bf16_t* W1T = (bf16_t*)(ws + 266240);                    // [2048][2560] bf16
  bf16_t* W2T = W1T + (size_t)HID * FIVE_D;                // [512][2048]  bf16
  bf16_t* Xc = W2T + (size_t)ND * HID;                     // [chunk][2560] bf16
  bf16_t* H1c = Xc + (size_t)chunk * FIVE_D;               // [chunk][2048] bf16

  float* out_states = (float*)d_out;                       // f32 output
  float* out_mask = out_states + (size_t)NB * NS * NL * ND;

  // Dynamic-LDS opt-in for the two GEMMs (host-side, idempotent).
  (void)hipFuncSetAttribute(
      reinterpret_cast<const void*>(gemm256_kernel<FIVE_D, HID>),
      hipFuncAttributeMaxDynamicSharedMemorySize, 131072);
  (void)hipFuncSetAttribute(
      reinterpret_cast<const void*>(gemm128_scatter_kernel<HID>),
      hipFuncAttributeMaxDynamicSharedMemorySize, 65536);

  // n_rows must start at 0 (ws is poisoned 0xAA before every launch).
  hipMemsetAsync(n_rows, 0, 4, stream);

  build_index_kernel<<<NB * NS, 256, 0, stream>>>(
      group_ids, lengths, n_rows, row_src, row_dst, empty_tokens, pos_emb,
      seq_id_emb, out_states, out_mask);

  transpose_cvt_kernel<FIVE_D, HID>
      <<<dim3(HID / 32, FIVE_D / 32), 256, 0, stream>>>(w1, W1T);
  transpose_cvt_kernel<HID, ND>
      <<<dim3(ND / 32, HID / 32), 256, 0, stream>>>(w2, W2T);

  for (int c = 0; c < nchunk; ++c) {
    int row_base = c * chunk;
    gather_ln_kernel<<<4096, 128, 0, stream>>>(
        embed_table, time_gap_emb, history_tokens, post_tokens, author_tokens,
        action_tokens, time_gap, ln_gamma, ln_beta, n_rows, row_src, row_base,
        chunk, Xc);

    gemm256_kernel<FIVE_D, HID>
        <<<dim3(HID / 256, chunk / 256), 512, 131072, stream>>>(
            Xc, W1T, n_rows, row_base, b1, H1c);

    gemm128_scatter_kernel<HID>
        <<<dim3(ND / 128, chunk / 128), 512, 65536, stream>>>(
            H1c, W2T, n_rows, row_base, b2, row_dst, pos_emb, seq_id_emb,
            out_states);
  }
}

// Round 8
// 400.969 us; speedup vs baseline: 1.1400x; 1.0227x over previous
//
#include <hip/hip_runtime.h>
#include <hip/hip_bf16.h>
#include <stdint.h>

// Problem constants
#define NB 32
#define NL 256
#define NS 4
#define ND 512
#define NH 1024           // NL * NS
#define FIVE_D 2560
#define HID 2048
#define MMAX 32768        // NB * NS * NL (cap on compact rows)

// Inputs: f32 / int32. OUTPUT: f32 (states [B,S,L,D] then mask [B,S,L]).
typedef __bf16 bf16_t;
typedef __bf16 bf16x4 __attribute__((ext_vector_type(4)));
typedef __bf16 bf16x8 __attribute__((ext_vector_type(8)));
typedef float f32x4 __attribute__((ext_vector_type(4)));

// async global->LDS, 16B per lane (wave-uniform base + lane*16 layout).
__device__ __forceinline__ void async_ld16(const void* g, void* l) {
  __builtin_amdgcn_global_load_lds(
      (__attribute__((address_space(1))) void*)(uintptr_t)g,
      (__attribute__((address_space(3))) void*)(uintptr_t)l, 16, 0, 0);
}

// ---------------------------------------------------------------------------
// K1: build compact row index + background fill + mask (merged fill_bg).
// ---------------------------------------------------------------------------
__global__ void build_index_kernel(const int* __restrict__ group_ids,
                                   const int* __restrict__ lengths,
                                   int* __restrict__ n_rows,
                                   int* __restrict__ row_src,
                                   int* __restrict__ row_dst,
                                   const float* __restrict__ empty_tokens,
                                   const float* __restrict__ pos_emb,
                                   const float* __restrict__ seq_emb,
                                   float* __restrict__ out,
                                   float* __restrict__ mask) {
  const int g = blockIdx.x;            // b*NS + s
  const int b = g >> 2, s = g & 3;
  const int t = threadIdx.x;           // 0..255
  const int lane = t & 63, w = t >> 6; // 4 waves
  int len = lengths[b];
  len = len < 0 ? 0 : (len > NH ? NH : len);
  const int* gi = group_ids + b * NH;

  __shared__ int wtot[16];             // per (chunk, wave) match counts
  __shared__ int sbase;

  bool valid[4];
#pragma unroll
  for (int c = 0; c < 4; ++c) {
    int h = c * 256 + t;
    valid[c] = (h < len) && (gi[h] == s + 1);
    unsigned long long m = __ballot(valid[c]);
    if (lane == 0) wtot[c * 4 + w] = __popcll(m);
  }
  __syncthreads();

  int pre[16];
  int run = 0;
#pragma unroll
  for (int i = 0; i < 16; ++i) { pre[i] = run; run += wtot[i]; }
  const int count = run;
  const int keff = count < NL ? count : NL;
  const int offset = count - keff;     // max(count - L, 0)

  if (t == 0) sbase = atomicAdd(n_rows, keff);
  __syncthreads();
  const int base = sbase;

  const unsigned long long lt = (1ull << lane) - 1ull;
#pragma unroll
  for (int c = 0; c < 4; ++c) {
    unsigned long long m = __ballot(valid[c]);
    if (valid[c]) {
      int rank = pre[c * 4 + w] + __popcll(m & lt);
      if (rank >= offset) {
        int slot = rank - offset;
        row_src[base + slot] = b * NH + c * 256 + t;
        row_dst[base + slot] = g * NL + slot;
      }
    }
  }

  // ---- merged background fill ----
  const bool empty = (count == 0);
  const int keptm = empty ? 1 : keff;
  mask[g * NL + t] = (t < keptm) ? 1.f : 0.f;      // t in [0,256)=L

  float* basep = out + (size_t)g * NL * ND;
  if (empty) {
    for (int d = t; d < ND; d += 256)
      basep[d] = empty_tokens[s * ND + d] + pos_emb[d] +
                 seq_emb[(s + 1) * ND + d];
  }
  int start = empty ? 1 : keff;
  uint4* p = (uint4*)basep;        // one slot = 128 uint4
  uint4 z; z.x = z.y = z.z = z.w = 0u;
  for (int i = start * (ND / 4) + t; i < NL * (ND / 4); i += 256) p[i] = z;
}

// ---------------------------------------------------------------------------
// K2: f32 [K,N] -> bf16 [N,K] tiled transpose (weights).
// ---------------------------------------------------------------------------
template <int KD, int NDIM>
__global__ void transpose_cvt_kernel(const float* __restrict__ src,
                                     bf16_t* __restrict__ dst) {
  __shared__ float tile[32][33];
  int k0 = blockIdx.y * 32, n0 = blockIdx.x * 32;
  int tx = threadIdx.x & 31, ty = threadIdx.x >> 5;   // 32 x 8
#pragma unroll
  for (int i = 0; i < 32; i += 8)
    tile[ty + i][tx] = src[(size_t)(k0 + ty + i) * NDIM + n0 + tx];
  __syncthreads();
#pragma unroll
  for (int i = 0; i < 32; i += 8)
    dst[(size_t)(n0 + ty + i) * KD + k0 + tx] = (bf16_t)tile[tx][ty + i];
}

// ---------------------------------------------------------------------------
// K3: gather 5 f32 embeddings + LayerNorm -> bf16 X[r_local, 2560]
// Block-per-row, every index compile-time static (rule #20), 128 thr,
// 5 named float4 loads, 1 sync/row via parity LDS slots.  (verified r7)
// ---------------------------------------------------------------------------
__launch_bounds__(128)
__global__ void gather_ln_kernel(const float* __restrict__ embed,
                                 const float* __restrict__ tg_emb,
                                 const int* __restrict__ ht,
                                 const int* __restrict__ pt,
                                 const int* __restrict__ at,
                                 const int* __restrict__ ct,
                                 const int* __restrict__ tg,
                                 const float* __restrict__ gamma,
                                 const float* __restrict__ beta,
                                 const int* __restrict__ n_rows,
                                 const int* __restrict__ row_src,
                                 int row_base, int chunk,
                                 bf16_t* __restrict__ X) {
  const int t = threadIdx.x;           // 0..127
  const int w = t >> 6;                // wave 0..1
  const int M = *n_rows;
  int lim = row_base + chunk;
  if (lim > M) lim = M;

  __shared__ float red2[2][4];         // [parity][sum0,sum1,sq0,sq1]
  int par = 0;

  const int o = t * 4;                 // float offset within a 512-float seg

  for (int r = row_base + blockIdx.x; r < lim; r += gridDim.x) {
    const int rl = r - row_base;
    const int pos = row_src[r];

    const float* s0 = embed + (size_t)ht[pos] * ND;
    const float* s1 = embed + (size_t)pt[pos] * ND;
    const float* s2 = embed + (size_t)at[pos] * ND;
    const float* s3 = embed + (size_t)ct[pos] * ND;
    int tgv = tg[pos];
    tgv = tgv < 0 ? 0 : (tgv > 128 ? 128 : tgv);
    const float* s4 = tg_emb + (size_t)tgv * ND;

    float4 v0 = *(const float4*)(s0 + o);
    float4 v1 = *(const float4*)(s1 + o);
    float4 v2 = *(const float4*)(s2 + o);
    float4 v3 = *(const float4*)(s3 + o);
    float4 v4 = *(const float4*)(s4 + o);

    float sum = v0.x + v0.y + v0.z + v0.w + v1.x + v1.y + v1.z + v1.w +
                v2.x + v2.y + v2.z + v2.w + v3.x + v3.y + v3.z + v3.w +
                v4.x + v4.y + v4.z + v4.w;
    float sq = v0.x * v0.x + v0.y * v0.y + v0.z * v0.z + v0.w * v0.w +
               v1.x * v1.x + v1.y * v1.y + v1.z * v1.z + v1.w * v1.w +
               v2.x * v2.x + v2.y * v2.y + v2.z * v2.z + v2.w * v2.w +
               v3.x * v3.x + v3.y * v3.y + v3.z * v3.z + v3.w * v3.w +
               v4.x * v4.x + v4.y * v4.y + v4.z * v4.z + v4.w * v4.w;
#pragma unroll
    for (int off = 32; off > 0; off >>= 1) {
      sum += __shfl_xor(sum, off);
      sq += __shfl_xor(sq, off);
    }
    if ((t & 63) == 0) { red2[par][w] = sum; red2[par][2 + w] = sq; }
    __syncthreads();                   // the ONLY sync per row
    const float S = red2[par][0] + red2[par][1];
    const float Q = red2[par][2] + red2[par][3];
    par ^= 1;
    const float mu = S * (1.f / FIVE_D);
    const float var = Q * (1.f / FIVE_D) - mu * mu;
    const float rstd = rsqrtf(var + 1e-5f);

    bf16_t* xr = X + (size_t)rl * FIVE_D;
#define LN_STORE(vk, kk)                                                     \
    do {                                                                     \
      float4 gm = *(const float4*)(gamma + (kk)*512 + o);                    \
      float4 bt = *(const float4*)(beta + (kk)*512 + o);                     \
      bf16x4 ov;                                                             \
      ov[0] = (bf16_t)((vk.x - mu) * rstd * gm.x + bt.x);                    \
      ov[1] = (bf16_t)((vk.y - mu) * rstd * gm.y + bt.y);                    \
      ov[2] = (bf16_t)((vk.z - mu) * rstd * gm.z + bt.z);                    \
      ov[3] = (bf16_t)((vk.w - mu) * rstd * gm.w + bt.w);                    \
      *(bf16x4*)(xr + (kk)*512 + o) = ov;                                    \
    } while (0)
    LN_STORE(v0, 0);
    LN_STORE(v1, 1);
    LN_STORE(v2, 2);
    LN_STORE(v3, 3);
    LN_STORE(v4, 4);
#undef LN_STORE
  }
}

// ---------------------------------------------------------------------------
// Shared sync macros.  v4 ledger (verified): one counted wait per K-tile
// covering the ENTIRE previous-staged tile; A-stage ahead of the wait,
// B-stage right AFTER the wait.  vmcnt never reaches 0 in the main loop.
// ---------------------------------------------------------------------------
#define FENCE asm volatile("" ::: "memory")
#define BARRIER do { FENCE; __builtin_amdgcn_s_barrier(); FENCE; } while (0)
#define WAIT_VM(n) asm volatile("s_waitcnt vmcnt(" #n ")" ::: "memory")

// ---------------------------------------------------------------------------
// K4a: 256x256 MFMA GEMM, counted-vmcnt double-buffered schedule (plain HIP).
// ROUND-8 CHANGE (T1, index-only): blockIdx.x is now the M-panel and
// blockIdx.y the N-panel.  The 8 blocks sharing one A-panel are strided by
// gridDim.x=128 in linear bid, and 128 % 8 == 0, so under round-robin
// bid->XCD they all land on the SAME XCD: the A-panel is fetched into that
// XCD's L2 once instead of once per XCD (A re-fetch was ~672 MB of the
// ~1.3 GB/dispatch L2/L3 delivery = the ~8.6 TB/s cache-BW wall).
// Active M-panels spread over XCDs via x%8, so no idle XCDs despite M being
// device-side only.  Schedule/sync UNCHANGED (verified ledger).
// ---------------------------------------------------------------------------
template <int KD, int LDC>
__launch_bounds__(512, 2)
__global__ void gemm256_kernel(const bf16_t* __restrict__ A,
                               const bf16_t* __restrict__ Bt,
                               const int* __restrict__ nrows_p,
                               int row_base,
                               const float* __restrict__ bias,
                               bf16_t* __restrict__ Cb) {
  static_assert(KD % 64 == 0 && KD / 64 >= 2, "KD");
  const int M = *nrows_p;
  const int m0 = blockIdx.x * 256;       // M-panel on x (fast axis)
  if (row_base + m0 >= M) return;
  const int n0 = blockIdx.y * 256;       // N-panel on y

  extern __shared__ char smem[];   // [2][ A 32KB | B 32KB ] = 128 KiB

  const int t = threadIdx.x;        // 0..511
  const int lane = t & 63;
  const int wv = t >> 6;            // 0..7
  const int wm = wv >> 2;           // 0..1  (M half)
  const int wn = wv & 3;            // 0..3  (N quarter)
  const int l15 = lane & 15;
  const int l4 = lane >> 4;

  const int r0 = t >> 3;               // 0..63 (j=1 adds 64 rows: (r&7) same)
  const int sq = (t & 7) ^ (r0 & 7);   // inverse-swizzled global chunk
  const bf16_t* Ab = A + (size_t)(m0 + r0) * KD + sq * 8;
  const bf16_t* Bb = Bt + (size_t)(n0 + r0) * KD + sq * 8;
  const int dst16 = t * 16;

  const int cs0 = (l4 ^ (l15 & 7)) << 4;   // ks=0 swizzled byte slot
  const int cs1 = cs0 ^ 64;                // ks=1
  const int arow = (wm * 128 + l15) * 128; // A row byte base for this wave
  const int brow = (wn * 64 + l15) * 128;  // B row byte base

  f32x4 acc[2][2][4][2] = {};              // [mh][nh][i][jj]
  bf16x8 a[4][2], bl[2][2], bh[2][2];

#define STAGE_A(dbuf, h, kofs)                                               \
  do {                                                                       \
    char* _d = smem + (dbuf) * 65536 + (h) * 16384 + dst16;                  \
    async_ld16(Ab + (size_t)((h) * 128) * KD + (kofs), _d);                  \
    async_ld16(Ab + (size_t)((h) * 128 + 64) * KD + (kofs), _d + 8192);      \
  } while (0)
#define STAGE_B(dbuf, h, kofs)                                               \
  do {                                                                       \
    char* _d = smem + (dbuf) * 65536 + 32768 + (h) * 16384 + dst16;          \
    async_ld16(Bb + (size_t)((h) * 128) * KD + (kofs), _d);                  \
    async_ld16(Bb + (size_t)((h) * 128 + 64) * KD + (kofs), _d + 8192);      \
  } while (0)
#define LOAD_A(cbuf, mh)                                                     \
  do {                                                                       \
    const char* _s = smem + (cbuf) * 65536 + (mh) * 8192 + arow;             \
    _Pragma("unroll") for (int _i = 0; _i < 4; ++_i) {                       \
      a[_i][0] = *(const bf16x8*)(_s + _i * 2048 + cs0);                     \
      a[_i][1] = *(const bf16x8*)(_s + _i * 2048 + cs1);                     \
    }                                                                        \
  } while (0)
#define LOAD_B(dst, cbuf, nh)                                                \
  do {                                                                       \
    const char* _s = smem + (cbuf) * 65536 + 32768 + (nh) * 4096 + brow;     \
    _Pragma("unroll") for (int _j = 0; _j < 2; ++_j) {                       \
      dst[_j][0] = *(const bf16x8*)(_s + _j * 2048 + cs0);                   \
      dst[_j][1] = *(const bf16x8*)(_s + _j * 2048 + cs1);                   \
    }                                                                        \
  } while (0)
#define MMA(mh, nh, B)                                                       \
  do {                                                                       \
    _Pragma("unroll") for (int _i = 0; _i < 4; ++_i)                         \
    _Pragma("unroll") for (int _j = 0; _j < 2; ++_j) {                       \
      acc[mh][nh][_i][_j] = __builtin_amdgcn_mfma_f32_16x16x32_bf16(         \
          a[_i][0], B[_j][0], acc[mh][nh][_i][_j], 0, 0, 0);                 \
      acc[mh][nh][_i][_j] = __builtin_amdgcn_mfma_f32_16x16x32_bf16(         \
          a[_i][1], B[_j][1], acc[mh][nh][_i][_j], 0, 0, 0);                 \
    }                                                                        \
  } while (0)

  constexpr int NT = KD / 64;

  // prologue: stage tile 0 into buf 0 (8 loads: Alo, Ahi, Blo, Bhi)
  STAGE_A(0, 0, 0);
  STAGE_A(0, 1, 0);
  STAGE_B(0, 0, 0);
  STAGE_B(0, 1, 0);

  int c = 0;
  for (int tk = 1; tk < NT; ++tk) {  // compute tile tk-1 (buf c), stage tk
    const int kn = tk * 64;
    const int d = c ^ 1;
    // stage A-halves of next tile: outstanding 8 -> 12
    STAGE_A(d, 0, kn);
    STAGE_A(d, 1, kn);
    WAIT_VM(4);      // retire exactly the previous tile's 8 loads (this wave)
    BARRIER;         // join: ALL waves' tile-c loads have landed in LDS
    // quadrant (m-lo, n-lo)
    LOAD_A(c, 0);
    LOAD_B(bl, c, 0);
    __builtin_amdgcn_s_setprio(1);
    MMA(0, 0, bl);
    __builtin_amdgcn_s_setprio(0);
    // stage B-halves of next tile EARLY in compute (after the wait, so this
    // traffic never sits ahead of a blocked wait): outstanding 4 -> 8
    STAGE_B(d, 0, kn);
    STAGE_B(d, 1, kn);
    // quadrant (m-lo, n-hi)
    LOAD_B(bh, c, 1);
    __builtin_amdgcn_s_setprio(1);
    MMA(0, 1, bh);
    __builtin_amdgcn_s_setprio(0);
    // quadrants (m-hi, n-hi) and (m-hi, n-lo)
    LOAD_A(c, 1);
    __builtin_amdgcn_s_setprio(1);
    MMA(1, 1, bh);
    MMA(1, 0, bl);
    __builtin_amdgcn_s_setprio(0);
    BARRIER;         // WAR: all reads of buf c done before tk+1 writes buf c
    c = d;
  }

  // peeled last tile: its 8 loads are the only outstanding ones
  WAIT_VM(0);
  BARRIER;
  LOAD_A(c, 0);
  LOAD_B(bl, c, 0);
  MMA(0, 0, bl);
  LOAD_B(bh, c, 1);
  MMA(0, 1, bh);
  LOAD_A(c, 1);
  MMA(1, 1, bh);
  MMA(1, 0, bl);

  // epilogue: bias + SiLU -> bf16 (rows beyond M are garbage; GEMM2 guards)
#pragma unroll
  for (int mh = 0; mh < 2; ++mh)
#pragma unroll
    for (int i = 0; i < 4; ++i) {
      const int rbase = m0 + wm * 128 + mh * 64 + i * 16 + l4 * 4;
#pragma unroll
      for (int nh = 0; nh < 2; ++nh)
#pragma unroll
        for (int j = 0; j < 2; ++j) {
          const int n = n0 + wn * 64 + nh * 32 + j * 16 + l15;
          const float bn = bias[n];
#pragma unroll
          for (int q = 0; q < 4; ++q) {
            float v = acc[mh][nh][i][j][q] + bn;
            v = v / (1.f + __expf(-v));              // SiLU
            Cb[(size_t)(rbase + q) * LDC + n] = (bf16_t)v;
          }
        }
    }
#undef STAGE_A
#undef STAGE_B
#undef LOAD_A
#undef LOAD_B
#undef MMA
}

// ---------------------------------------------------------------------------
// K4b: 128x128 MFMA GEMM for GEMM2 (N=512), same counted-vmcnt ledger.
// Same T1 axis-swap: blockIdx.x = M-panel (stride-256 same-A siblings ->
// same XCD), blockIdx.y = N-panel.
// ---------------------------------------------------------------------------
template <int KD>
__launch_bounds__(512, 2)
__global__ void gemm128_scatter_kernel(const bf16_t* __restrict__ A,
                                       const bf16_t* __restrict__ Bt,
                                       const int* __restrict__ nrows_p,
                                       int row_base,
                                       const float* __restrict__ bias,
                                       const int* __restrict__ row_dst,
                                       const float* __restrict__ pos_emb,
                                       const float* __restrict__ seq_emb,
                                       float* __restrict__ out) {
  static_assert(KD % 64 == 0 && KD / 64 >= 2, "KD");
  const int M = *nrows_p;
  const int m0 = blockIdx.x * 128;       // M-panel on x (fast axis)
  if (row_base + m0 >= M) return;
  const int n0 = blockIdx.y * 128;       // N-panel on y

  extern __shared__ char smem[];   // [2][ A 16KB | B 16KB ] = 64 KiB

  const int t = threadIdx.x;        // 0..511
  const int lane = t & 63;
  const int wv = t >> 6;            // 0..7
  const int wm = wv >> 1;           // 0..3  (M quarter, 32 rows)
  const int wn = wv & 1;            // 0..1  (N half, 64 cols)
  const int l15 = lane & 15;
  const int l4 = lane >> 4;

  const int r0 = t >> 3;               // 0..63
  const int sq = (t & 7) ^ (r0 & 7);
  const bf16_t* Ab = A + (size_t)(m0 + r0) * KD + sq * 8;
  const bf16_t* Bb = Bt + (size_t)(n0 + r0) * KD + sq * 8;
  const int dst16 = t * 16;

  const int cs0 = (l4 ^ (l15 & 7)) << 4;   // ks=0 swizzled byte slot
  const int cs1 = cs0 ^ 64;                // ks=1
  const int arow = (wm * 32 + l15) * 128;  // A row byte base for this wave
  const int brow = (wn * 64 + l15) * 128;  // B row byte base

  f32x4 acc[2][4] = {};                    // [i (16-row frag)][j (16-col frag)]
  bf16x8 a[2][2], b[4][2];

#define STAGE_A2(dbuf, kofs)                                                 \
  do {                                                                       \
    char* _d = smem + (dbuf) * 32768 + dst16;                                \
    async_ld16(Ab + (kofs), _d);                                             \
    async_ld16(Ab + (size_t)64 * KD + (kofs), _d + 8192);                    \
  } while (0)
#define STAGE_B2(dbuf, kofs)                                                 \
  do {                                                                       \
    char* _d = smem + (dbuf) * 32768 + 16384 + dst16;                        \
    async_ld16(Bb + (kofs), _d);                                             \
    async_ld16(Bb + (size_t)64 * KD + (kofs), _d + 8192);                    \
  } while (0)
#define LOAD_A2(cbuf)                                                        \
  do {                                                                       \
    const char* _s = smem + (cbuf) * 32768 + arow;                           \
    _Pragma("unroll") for (int _i = 0; _i < 2; ++_i) {                       \
      a[_i][0] = *(const bf16x8*)(_s + _i * 2048 + cs0);                     \
      a[_i][1] = *(const bf16x8*)(_s + _i * 2048 + cs1);                     \
    }                                                                        \
  } while (0)
#define LOAD_B2(cbuf)                                                        \
  do {                                                                       \
    const char* _s = smem + (cbuf) * 32768 + 16384 + brow;                   \
    _Pragma("unroll") for (int _j = 0; _j < 4; ++_j) {                       \
      b[_j][0] = *(const bf16x8*)(_s + _j * 2048 + cs0);                     \
      b[_j][1] = *(const bf16x8*)(_s + _j * 2048 + cs1);                     \
    }                                                                        \
  } while (0)
#define MMA2                                                                 \
  do {                                                                       \
    _Pragma("unroll") for (int _i = 0; _i < 2; ++_i)                         \
    _Pragma("unroll") for (int _j = 0; _j < 4; ++_j) {                       \
      acc[_i][_j] = __builtin_amdgcn_mfma_f32_16x16x32_bf16(                 \
          a[_i][0], b[_j][0], acc[_i][_j], 0, 0, 0);                         \
      acc[_i][_j] = __builtin_amdgcn_mfma_f32_16x16x32_bf16(                 \
          a[_i][1], b[_j][1], acc[_i][_j], 0, 0, 0);                         \
    }                                                                        \
  } while (0)

  constexpr int NT = KD / 64;

  // prologue: stage tile 0 (4 loads)
  STAGE_A2(0, 0);
  STAGE_B2(0, 0);

  int c = 0;
  for (int tk = 1; tk < NT; ++tk) {
    const int kn = tk * 64;
    const int d = c ^ 1;
    STAGE_A2(d, kn);            // outstanding 4 -> 6
    WAIT_VM(2);                 // retire exactly the previous tile's 4 loads
    BARRIER;
    LOAD_A2(c);
    LOAD_B2(c);
    STAGE_B2(d, kn);            // issue B after the wait: 2 -> 4
    __builtin_amdgcn_s_setprio(1);
    MMA2;
    __builtin_amdgcn_s_setprio(0);
    BARRIER;                    // WAR before next iter writes buf c
    c = d;
  }

  WAIT_VM(0);
  BARRIER;
  LOAD_A2(c);
  LOAD_B2(c);
  MMA2;

  // epilogue: scatter rows via row_dst, +bias +pos_emb +seq_emb (f32 out)
#pragma unroll
  for (int i = 0; i < 2; ++i) {
    int mbase = m0 + wm * 32 + i * 16 + l4 * 4;     // local row
#pragma unroll
    for (int q = 0; q < 4; ++q) {
      int r = mbase + q;                            // local row
      if (row_base + r >= M) continue;
      int dst = row_dst[row_base + r];              // (b*S+s)*L + slot
      int slot = dst & (NL - 1);
      int sg = (dst >> 8) & 3;
#pragma unroll
      for (int j = 0; j < 4; ++j) {
        int n = n0 + wn * 64 + j * 16 + l15;
        float v = acc[i][j][q] + bias[n] + pos_emb[slot * ND + n] +
                  seq_emb[(sg + 1) * ND + n];
        out[(size_t)dst * ND + n] = v;              // f32 output
      }
    }
  }
#undef STAGE_A2
#undef STAGE_B2
#undef LOAD_A2
#undef LOAD_B2
#undef MMA2
}

// ---------------------------------------------------------------------------
extern "C" void kernel_launch(void* const* d_in, const int* in_sizes, int n_in,
                              void* d_out, int out_size, void* d_ws,
                              size_t ws_size, hipStream_t stream) {
  const float* embed_table = (const float*)d_in[0];
  const float* time_gap_emb = (const float*)d_in[1];
  const float* seq_id_emb = (const float*)d_in[2];
  const float* pos_emb = (const float*)d_in[3];
  const float* ln_gamma = (const float*)d_in[4];
  const float* ln_beta = (const float*)d_in[5];
  const float* w1 = (const float*)d_in[6];
  const float* b1 = (const float*)d_in[7];
  const float* w2 = (const float*)d_in[8];
  const float* b2 = (const float*)d_in[9];
  const float* empty_tokens = (const float*)d_in[10];
  const int* history_tokens = (const int*)d_in[11];
  const int* post_tokens = (const int*)d_in[12];
  const int* author_tokens = (const int*)d_in[13];
  const int* action_tokens = (const int*)d_in[14];
  const int* time_gap = (const int*)d_in[15];
  const int* group_ids = (const int*)d_in[16];
  const int* lengths = (const int*)d_in[17];

  // Runtime-adaptive chunking.  ws_size is constant across calls/replays, so
  // this branch is identical on every invocation (graph-capture safe).
  const size_t fixed = 266240 + (size_t)(HID * FIVE_D + ND * HID) * 2;
  int chunk, nchunk;
  if (ws_size >= fixed + (size_t)32768 * 9216) { chunk = 32768; nchunk = 1; }
  else if (ws_size >= fixed + (size_t)16384 * 9216) { chunk = 16384; nchunk = 2; }
  else { chunk = 8192; nchunk = 4; }

  char* ws = (char*)d_ws;
  int* n_rows = (int*)ws;                                  // 4 B
  int* row_src = (int*)(ws + 4096);                        // 32768*4 B
  int* row_dst = (int*)(ws + 4096 + 131072);               // 32768*4 B
  bf16_t* W1T = (bf16_t*)(ws + 266240);                    // [2048][2560] bf16
  bf16_t* W2T = W1T + (size_t)HID * FIVE_D;                // [512][2048]  bf16
  bf16_t* Xc = W2T + (size_t)ND * HID;                     // [chunk][2560] bf16
  bf16_t* H1c = Xc + (size_t)chunk * FIVE_D;               // [chunk][2048] bf16

  float* out_states = (float*)d_out;                       // f32 output
  float* out_mask = out_states + (size_t)NB * NS * NL * ND;

  // Dynamic-LDS opt-in for the two GEMMs (host-side, idempotent).
  (void)hipFuncSetAttribute(
      reinterpret_cast<const void*>(gemm256_kernel<FIVE_D, HID>),
      hipFuncAttributeMaxDynamicSharedMemorySize, 131072);
  (void)hipFuncSetAttribute(
      reinterpret_cast<const void*>(gemm128_scatter_kernel<HID>),
      hipFuncAttributeMaxDynamicSharedMemorySize, 65536);

  // n_rows must start at 0 (ws is poisoned 0xAA before every launch).
  hipMemsetAsync(n_rows, 0, 4, stream);

  build_index_kernel<<<NB * NS, 256, 0, stream>>>(
      group_ids, lengths, n_rows, row_src, row_dst, empty_tokens, pos_emb,
      seq_id_emb, out_states, out_mask);

  transpose_cvt_kernel<FIVE_D, HID>
      <<<dim3(HID / 32, FIVE_D / 32), 256, 0, stream>>>(w1, W1T);
  transpose_cvt_kernel<HID, ND>
      <<<dim3(ND / 32, HID / 32), 256, 0, stream>>>(w2, W2T);

  for (int c = 0; c < nchunk; ++c) {
    int row_base = c * chunk;
    gather_ln_kernel<<<4096, 128, 0, stream>>>(
        embed_table, time_gap_emb, history_tokens, post_tokens, author_tokens,
        action_tokens, time_gap, ln_gamma, ln_beta, n_rows, row_src, row_base,
        chunk, Xc);

    // M-panels on x (fast axis): same-A siblings share an XCD (T1).
    gemm256_kernel<FIVE_D, HID>
        <<<dim3(chunk / 256, HID / 256), 512, 131072, stream>>>(
            Xc, W1T, n_rows, row_base, b1, H1c);

    gemm128_scatter_kernel<HID>
        <<<dim3(chunk / 128, ND / 128), 512, 65536, stream>>>(
            H1c, W2T, n_rows, row_base, b2, row_dst, pos_emb, seq_id_emb,
            out_states);
  }
}

// Round 9
// 395.767 us; speedup vs baseline: 1.1550x; 1.0131x over previous
//
#include <hip/hip_runtime.h>
#include <hip/hip_bf16.h>
#include <stdint.h>

// Problem constants
#define NB 32
#define NL 256
#define NS 4
#define ND 512
#define NH 1024           // NL * NS
#define FIVE_D 2560
#define HID 2048
#define MMAX 32768        // NB * NS * NL (cap on compact rows)

// Inputs: f32 / int32. OUTPUT: f32 (states [B,S,L,D] then mask [B,S,L]).
typedef __bf16 bf16_t;
typedef __bf16 bf16x4 __attribute__((ext_vector_type(4)));
typedef __bf16 bf16x8 __attribute__((ext_vector_type(8)));
typedef float f32x4 __attribute__((ext_vector_type(4)));

// async global->LDS, 16B per lane (wave-uniform base + lane*16 layout).
__device__ __forceinline__ void async_ld16(const void* g, void* l) {
  __builtin_amdgcn_global_load_lds(
      (__attribute__((address_space(1))) void*)(uintptr_t)g,
      (__attribute__((address_space(3))) void*)(uintptr_t)l, 16, 0, 0);
}

// ---------------------------------------------------------------------------
// K1: build compact row index + background fill + mask.
// ROUND-9: 4 blocks per (b,s) group (512 total).  Every block recounts its
// group (4KB scan, trivial); quarter 0 emits the index/mask/empty-token;
// the 33 MB zero-fill is split across the 4 quarters (was 128 blocks = half
// the CUs; fill store-parallelism x4).
// ---------------------------------------------------------------------------
__global__ void build_index_kernel(const int* __restrict__ group_ids,
                                   const int* __restrict__ lengths,
                                   int* __restrict__ n_rows,
                                   int* __restrict__ row_src,
                                   int* __restrict__ row_dst,
                                   const float* __restrict__ empty_tokens,
                                   const float* __restrict__ pos_emb,
                                   const float* __restrict__ seq_emb,
                                   float* __restrict__ out,
                                   float* __restrict__ mask) {
  const int g = blockIdx.x >> 2;       // group: b*NS + s
  const int qtr = blockIdx.x & 3;      // fill quarter
  const int b = g >> 2, s = g & 3;
  const int t = threadIdx.x;           // 0..255
  const int lane = t & 63, w = t >> 6; // 4 waves
  int len = lengths[b];
  len = len < 0 ? 0 : (len > NH ? NH : len);
  const int* gi = group_ids + b * NH;

  __shared__ int wtot[16];             // per (chunk, wave) match counts
  __shared__ int sbase;

  bool valid[4];
#pragma unroll
  for (int c = 0; c < 4; ++c) {
    int h = c * 256 + t;
    valid[c] = (h < len) && (gi[h] == s + 1);
    unsigned long long m = __ballot(valid[c]);
    if (lane == 0) wtot[c * 4 + w] = __popcll(m);
  }
  __syncthreads();

  int pre[16];
  int run = 0;
#pragma unroll
  for (int i = 0; i < 16; ++i) { pre[i] = run; run += wtot[i]; }
  const int count = run;
  const int keff = count < NL ? count : NL;
  const int offset = count - keff;     // max(count - L, 0)

  const bool empty = (count == 0);
  const int start = empty ? 1 : keff;

  if (qtr == 0) {
    if (t == 0) sbase = atomicAdd(n_rows, keff);
    __syncthreads();
    const int base = sbase;

    const unsigned long long lt = (1ull << lane) - 1ull;
#pragma unroll
    for (int c = 0; c < 4; ++c) {
      unsigned long long m = __ballot(valid[c]);
      if (valid[c]) {
        int rank = pre[c * 4 + w] + __popcll(m & lt);
        if (rank >= offset) {
          int slot = rank - offset;
          row_src[base + slot] = b * NH + c * 256 + t;
          row_dst[base + slot] = g * NL + slot;
        }
      }
    }

    const int keptm = empty ? 1 : keff;
    mask[g * NL + t] = (t < keptm) ? 1.f : 0.f;    // t in [0,256)=L

    if (empty) {
      float* basep = out + (size_t)g * NL * ND;
      for (int d = t; d < ND; d += 256)
        basep[d] = empty_tokens[s * ND + d] + pos_emb[d] +
                   seq_emb[(s + 1) * ND + d];
    }
  }

  // zero-fill: this quarter covers slots [qtr*64, qtr*64+64) clamped to
  // [start, 256).  One slot = 128 uint4.
  int lo = qtr * 64; if (lo < start) lo = start;
  const int hi = qtr * 64 + 64;
  if (lo < hi) {
    uint4* p = (uint4*)(out + (size_t)g * NL * ND);
    uint4 z; z.x = z.y = z.z = z.w = 0u;
    for (int i = lo * (ND / 4) + t; i < hi * (ND / 4); i += 256) p[i] = z;
  }
}

// ---------------------------------------------------------------------------
// K2: f32 [K,N] -> bf16 [N,K] tiled transpose (weights).
// ---------------------------------------------------------------------------
template <int KD, int NDIM>
__global__ void transpose_cvt_kernel(const float* __restrict__ src,
                                     bf16_t* __restrict__ dst) {
  __shared__ float tile[32][33];
  int k0 = blockIdx.y * 32, n0 = blockIdx.x * 32;
  int tx = threadIdx.x & 31, ty = threadIdx.x >> 5;   // 32 x 8
#pragma unroll
  for (int i = 0; i < 32; i += 8)
    tile[ty + i][tx] = src[(size_t)(k0 + ty + i) * NDIM + n0 + tx];
  __syncthreads();
#pragma unroll
  for (int i = 0; i < 32; i += 8)
    dst[(size_t)(n0 + ty + i) * KD + k0 + tx] = (bf16_t)tile[tx][ty + i];
}

// ---------------------------------------------------------------------------
// K3: gather 5 f32 embeddings + LayerNorm -> bf16 X[r_local, 2560]
// ROUND-9: WAVE-PER-ROW, rule-#20-clean (the r6 idea done right): 10 NAMED
// float4 loads with LITERAL segment + offset per load (zero runtime array
// indexing -> registers by construction), no LDS, no __syncthreads,
// 64-lane butterfly reduce.  8192 waves in flight = 2x r7's row
// parallelism, no per-row sync serialization.
// Element map: load k covers floats [k*256 + lane*4, +4) of the 2560-row;
// segment = k/2 (k=8,9 -> tg_emb), offset (k&1)*256 + lane*4 — all literal.
// ---------------------------------------------------------------------------
__launch_bounds__(256)
__global__ void gather_ln_kernel(const float* __restrict__ embed,
                                 const float* __restrict__ tg_emb,
                                 const int* __restrict__ ht,
                                 const int* __restrict__ pt,
                                 const int* __restrict__ at,
                                 const int* __restrict__ ct,
                                 const int* __restrict__ tg,
                                 const float* __restrict__ gamma,
                                 const float* __restrict__ beta,
                                 const int* __restrict__ n_rows,
                                 const int* __restrict__ row_src,
                                 int row_base, int chunk,
                                 bf16_t* __restrict__ X) {
  const int l = threadIdx.x & 63;              // lane
  const int wid = blockIdx.x * 4 + (threadIdx.x >> 6);
  const int wstride = gridDim.x * 4;
  const int M = *n_rows;
  int lim = row_base + chunk;
  if (lim > M) lim = M;

  const int o = l * 4;                         // float offset within 256-span

  for (int r = row_base + wid; r < lim; r += wstride) {
    const int rl = r - row_base;
    const int pos = row_src[r];

    const float* s0 = embed + (size_t)ht[pos] * ND;
    const float* s1 = embed + (size_t)pt[pos] * ND;
    const float* s2 = embed + (size_t)at[pos] * ND;
    const float* s3 = embed + (size_t)ct[pos] * ND;
    int tgv = tg[pos];
    tgv = tgv < 0 ? 0 : (tgv > 128 ? 128 : tgv);
    const float* s4 = tg_emb + (size_t)tgv * ND;

    // 10 independent 16B loads, named, literal seg/offset.
    float4 v0 = *(const float4*)(s0 + o);
    float4 v1 = *(const float4*)(s0 + 256 + o);
    float4 v2 = *(const float4*)(s1 + o);
    float4 v3 = *(const float4*)(s1 + 256 + o);
    float4 v4 = *(const float4*)(s2 + o);
    float4 v5 = *(const float4*)(s2 + 256 + o);
    float4 v6 = *(const float4*)(s3 + o);
    float4 v7 = *(const float4*)(s3 + 256 + o);
    float4 v8 = *(const float4*)(s4 + o);
    float4 v9 = *(const float4*)(s4 + 256 + o);

    float sum = 0.f, sq = 0.f;
#define ACC(vk)                                                              \
    do {                                                                     \
      sum += vk.x + vk.y + vk.z + vk.w;                                      \
      sq += vk.x * vk.x + vk.y * vk.y + vk.z * vk.z + vk.w * vk.w;           \
    } while (0)
    ACC(v0); ACC(v1); ACC(v2); ACC(v3); ACC(v4);
    ACC(v5); ACC(v6); ACC(v7); ACC(v8); ACC(v9);
#undef ACC
#pragma unroll
    for (int off = 32; off > 0; off >>= 1) {
      sum += __shfl_xor(sum, off);
      sq += __shfl_xor(sq, off);
    }
    const float mu = sum * (1.f / FIVE_D);
    const float var = sq * (1.f / FIVE_D) - mu * mu;
    const float rstd = rsqrtf(var + 1e-5f);

    bf16_t* xr = X + (size_t)rl * FIVE_D;
#define LN_STORE(vk, kofs)                                                   \
    do {                                                                     \
      float4 gm = *(const float4*)(gamma + (kofs) + o);                      \
      float4 bt = *(const float4*)(beta + (kofs) + o);                       \
      bf16x4 ov;                                                             \
      ov[0] = (bf16_t)((vk.x - mu) * rstd * gm.x + bt.x);                    \
      ov[1] = (bf16_t)((vk.y - mu) * rstd * gm.y + bt.y);                    \
      ov[2] = (bf16_t)((vk.z - mu) * rstd * gm.z + bt.z);                    \
      ov[3] = (bf16_t)((vk.w - mu) * rstd * gm.w + bt.w);                    \
      *(bf16x4*)(xr + (kofs) + o) = ov;                                      \
    } while (0)
    LN_STORE(v0, 0);    LN_STORE(v1, 256);
    LN_STORE(v2, 512);  LN_STORE(v3, 768);
    LN_STORE(v4, 1024); LN_STORE(v5, 1280);
    LN_STORE(v6, 1536); LN_STORE(v7, 1792);
    LN_STORE(v8, 2048); LN_STORE(v9, 2304);
#undef LN_STORE
  }
}

// ---------------------------------------------------------------------------
// Shared sync macros.  v4 ledger (verified): one counted wait per K-tile
// covering the ENTIRE previous-staged tile; A-stage ahead of the wait,
// B-stage right AFTER the wait.  vmcnt never reaches 0 in the main loop.
// ---------------------------------------------------------------------------
#define FENCE asm volatile("" ::: "memory")
#define BARRIER do { FENCE; __builtin_amdgcn_s_barrier(); FENCE; } while (0)
#define WAIT_VM(n) asm volatile("s_waitcnt vmcnt(" #n ")" ::: "memory")

// ---------------------------------------------------------------------------
// K4a: 256x256 MFMA GEMM, counted-vmcnt double-buffered schedule (plain HIP).
// blockIdx.x = M-panel (fast axis; same-A siblings strided 128 = same XCD,
// T1 — round-8 verified: FETCH 220->94 MB = compulsory).
// ---------------------------------------------------------------------------
template <int KD, int LDC>
__launch_bounds__(512, 2)
__global__ void gemm256_kernel(const bf16_t* __restrict__ A,
                               const bf16_t* __restrict__ Bt,
                               const int* __restrict__ nrows_p,
                               int row_base,
                               const float* __restrict__ bias,
                               bf16_t* __restrict__ Cb) {
  static_assert(KD % 64 == 0 && KD / 64 >= 2, "KD");
  const int M = *nrows_p;
  const int m0 = blockIdx.x * 256;       // M-panel on x (fast axis)
  if (row_base + m0 >= M) return;
  const int n0 = blockIdx.y * 256;       // N-panel on y

  extern __shared__ char smem[];   // [2][ A 32KB | B 32KB ] = 128 KiB

  const int t = threadIdx.x;        // 0..511
  const int lane = t & 63;
  const int wv = t >> 6;            // 0..7
  const int wm = wv >> 2;           // 0..1  (M half)
  const int wn = wv & 3;            // 0..3  (N quarter)
  const int l15 = lane & 15;
  const int l4 = lane >> 4;

  const int r0 = t >> 3;               // 0..63 (j=1 adds 64 rows: (r&7) same)
  const int sq = (t & 7) ^ (r0 & 7);   // inverse-swizzled global chunk
  const bf16_t* Ab = A + (size_t)(m0 + r0) * KD + sq * 8;
  const bf16_t* Bb = Bt + (size_t)(n0 + r0) * KD + sq * 8;
  const int dst16 = t * 16;

  const int cs0 = (l4 ^ (l15 & 7)) << 4;   // ks=0 swizzled byte slot
  const int cs1 = cs0 ^ 64;                // ks=1
  const int arow = (wm * 128 + l15) * 128; // A row byte base for this wave
  const int brow = (wn * 64 + l15) * 128;  // B row byte base

  f32x4 acc[2][2][4][2] = {};              // [mh][nh][i][jj]
  bf16x8 a[4][2], bl[2][2], bh[2][2];

#define STAGE_A(dbuf, h, kofs)                                               \
  do {                                                                       \
    char* _d = smem + (dbuf) * 65536 + (h) * 16384 + dst16;                  \
    async_ld16(Ab + (size_t)((h) * 128) * KD + (kofs), _d);                  \
    async_ld16(Ab + (size_t)((h) * 128 + 64) * KD + (kofs), _d + 8192);      \
  } while (0)
#define STAGE_B(dbuf, h, kofs)                                               \
  do {                                                                       \
    char* _d = smem + (dbuf) * 65536 + 32768 + (h) * 16384 + dst16;          \
    async_ld16(Bb + (size_t)((h) * 128) * KD + (kofs), _d);                  \
    async_ld16(Bb + (size_t)((h) * 128 + 64) * KD + (kofs), _d + 8192);      \
  } while (0)
#define LOAD_A(cbuf, mh)                                                     \
  do {                                                                       \
    const char* _s = smem + (cbuf) * 65536 + (mh) * 8192 + arow;             \
    _Pragma("unroll") for (int _i = 0; _i < 4; ++_i) {                       \
      a[_i][0] = *(const bf16x8*)(_s + _i * 2048 + cs0);                     \
      a[_i][1] = *(const bf16x8*)(_s + _i * 2048 + cs1);                     \
    }                                                                        \
  } while (0)
#define LOAD_B(dst, cbuf, nh)                                                \
  do {                                                                       \
    const char* _s = smem + (cbuf) * 65536 + 32768 + (nh) * 4096 + brow;     \
    _Pragma("unroll") for (int _j = 0; _j < 2; ++_j) {                       \
      dst[_j][0] = *(const bf16x8*)(_s + _j * 2048 + cs0);                   \
      dst[_j][1] = *(const bf16x8*)(_s + _j * 2048 + cs1);                   \
    }                                                                        \
  } while (0)
#define MMA(mh, nh, B)                                                       \
  do {                                                                       \
    _Pragma("unroll") for (int _i = 0; _i < 4; ++_i)                         \
    _Pragma("unroll") for (int _j = 0; _j < 2; ++_j) {                       \
      acc[mh][nh][_i][_j] = __builtin_amdgcn_mfma_f32_16x16x32_bf16(         \
          a[_i][0], B[_j][0], acc[mh][nh][_i][_j], 0, 0, 0);                 \
      acc[mh][nh][_i][_j] = __builtin_amdgcn_mfma_f32_16x16x32_bf16(         \
          a[_i][1], B[_j][1], acc[mh][nh][_i][_j], 0, 0, 0);                 \
    }                                                                        \
  } while (0)

  constexpr int NT = KD / 64;

  // prologue: stage tile 0 into buf 0 (8 loads: Alo, Ahi, Blo, Bhi)
  STAGE_A(0, 0, 0);
  STAGE_A(0, 1, 0);
  STAGE_B(0, 0, 0);
  STAGE_B(0, 1, 0);

  int c = 0;
  for (int tk = 1; tk < NT; ++tk) {  // compute tile tk-1 (buf c), stage tk
    const int kn = tk * 64;
    const int d = c ^ 1;
    // stage A-halves of next tile: outstanding 8 -> 12
    STAGE_A(d, 0, kn);
    STAGE_A(d, 1, kn);
    WAIT_VM(4);      // retire exactly the previous tile's 8 loads (this wave)
    BARRIER;         // join: ALL waves' tile-c loads have landed in LDS
    // quadrant (m-lo, n-lo)
    LOAD_A(c, 0);
    LOAD_B(bl, c, 0);
    __builtin_amdgcn_s_setprio(1);
    MMA(0, 0, bl);
    __builtin_amdgcn_s_setprio(0);
    // stage B-halves of next tile EARLY in compute (after the wait, so this
    // traffic never sits ahead of a blocked wait): outstanding 4 -> 8
    STAGE_B(d, 0, kn);
    STAGE_B(d, 1, kn);
    // quadrant (m-lo, n-hi)
    LOAD_B(bh, c, 1);
    __builtin_amdgcn_s_setprio(1);
    MMA(0, 1, bh);
    __builtin_amdgcn_s_setprio(0);
    // quadrants (m-hi, n-hi) and (m-hi, n-lo)
    LOAD_A(c, 1);
    __builtin_amdgcn_s_setprio(1);
    MMA(1, 1, bh);
    MMA(1, 0, bl);
    __builtin_amdgcn_s_setprio(0);
    BARRIER;         // WAR: all reads of buf c done before tk+1 writes buf c
    c = d;
  }

  // peeled last tile: its 8 loads are the only outstanding ones
  WAIT_VM(0);
  BARRIER;
  LOAD_A(c, 0);
  LOAD_B(bl, c, 0);
  MMA(0, 0, bl);
  LOAD_B(bh, c, 1);
  MMA(0, 1, bh);
  LOAD_A(c, 1);
  MMA(1, 1, bh);
  MMA(1, 0, bl);

  // epilogue: bias + SiLU -> bf16 (rows beyond M are garbage; GEMM2 guards)
#pragma unroll
  for (int mh = 0; mh < 2; ++mh)
#pragma unroll
    for (int i = 0; i < 4; ++i) {
      const int rbase = m0 + wm * 128 + mh * 64 + i * 16 + l4 * 4;
#pragma unroll
      for (int nh = 0; nh < 2; ++nh)
#pragma unroll
        for (int j = 0; j < 2; ++j) {
          const int n = n0 + wn * 64 + nh * 32 + j * 16 + l15;
          const float bn = bias[n];
#pragma unroll
          for (int q = 0; q < 4; ++q) {
            float v = acc[mh][nh][i][j][q] + bn;
            v = v / (1.f + __expf(-v));              // SiLU
            Cb[(size_t)(rbase + q) * LDC + n] = (bf16_t)v;
          }
        }
    }
#undef STAGE_A
#undef STAGE_B
#undef LOAD_A
#undef LOAD_B
#undef MMA
}

// ---------------------------------------------------------------------------
// K4b: 128x128 MFMA GEMM for GEMM2 (N=512), same counted-vmcnt ledger.
// blockIdx.x = M-panel (same-A siblings strided 256 = same XCD).
// ---------------------------------------------------------------------------
template <int KD>
__launch_bounds__(512, 2)
__global__ void gemm128_scatter_kernel(const bf16_t* __restrict__ A,
                                       const bf16_t* __restrict__ Bt,
                                       const int* __restrict__ nrows_p,
                                       int row_base,
                                       const float* __restrict__ bias,
                                       const int* __restrict__ row_dst,
                                       const float* __restrict__ pos_emb,
                                       const float* __restrict__ seq_emb,
                                       float* __restrict__ out) {
  static_assert(KD % 64 == 0 && KD / 64 >= 2, "KD");
  const int M = *nrows_p;
  const int m0 = blockIdx.x * 128;       // M-panel on x (fast axis)
  if (row_base + m0 >= M) return;
  const int n0 = blockIdx.y * 128;       // N-panel on y

  extern __shared__ char smem[];   // [2][ A 16KB | B 16KB ] = 64 KiB

  const int t = threadIdx.x;        // 0..511
  const int lane = t & 63;
  const int wv = t >> 6;            // 0..7
  const int wm = wv >> 1;           // 0..3  (M quarter, 32 rows)
  const int wn = wv & 1;            // 0..1  (N half, 64 cols)
  const int l15 = lane & 15;
  const int l4 = lane >> 4;

  const int r0 = t >> 3;               // 0..63
  const int sq = (t & 7) ^ (r0 & 7);
  const bf16_t* Ab = A + (size_t)(m0 + r0) * KD + sq * 8;
  const bf16_t* Bb = Bt + (size_t)(n0 + r0) * KD + sq * 8;
  const int dst16 = t * 16;

  const int cs0 = (l4 ^ (l15 & 7)) << 4;   // ks=0 swizzled byte slot
  const int cs1 = cs0 ^ 64;                // ks=1
  const int arow = (wm * 32 + l15) * 128;  // A row byte base for this wave
  const int brow = (wn * 64 + l15) * 128;  // B row byte base

  f32x4 acc[2][4] = {};                    // [i (16-row frag)][j (16-col frag)]
  bf16x8 a[2][2], b[4][2];

#define STAGE_A2(dbuf, kofs)                                                 \
  do {                                                                       \
    char* _d = smem + (dbuf) * 32768 + dst16;                                \
    async_ld16(Ab + (kofs), _d);                                             \
    async_ld16(Ab + (size_t)64 * KD + (kofs), _d + 8192);                    \
  } while (0)
#define STAGE_B2(dbuf, kofs)                                                 \
  do {                                                                       \
    char* _d = smem + (dbuf) * 32768 + 16384 + dst16;                        \
    async_ld16(Bb + (kofs), _d);                                             \
    async_ld16(Bb + (size_t)64 * KD + (kofs), _d + 8192);                    \
  } while (0)
#define LOAD_A2(cbuf)                                                        \
  do {                                                                       \
    const char* _s = smem + (cbuf) * 32768 + arow;                           \
    _Pragma("unroll") for (int _i = 0; _i < 2; ++_i) {                       \
      a[_i][0] = *(const bf16x8*)(_s + _i * 2048 + cs0);                     \
      a[_i][1] = *(const bf16x8*)(_s + _i * 2048 + cs1);                     \
    }                                                                        \
  } while (0)
#define LOAD_B2(cbuf)                                                        \
  do {                                                                       \
    const char* _s = smem + (cbuf) * 32768 + 16384 + brow;                   \
    _Pragma("unroll") for (int _j = 0; _j < 4; ++_j) {                       \
      b[_j][0] = *(const bf16x8*)(_s + _j * 2048 + cs0);                     \
      b[_j][1] = *(const bf16x8*)(_s + _j * 2048 + cs1);                     \
    }                                                                        \
  } while (0)
#define MMA2                                                                 \
  do {                                                                       \
    _Pragma("unroll") for (int _i = 0; _i < 2; ++_i)                         \
    _Pragma("unroll") for (int _j = 0; _j < 4; ++_j) {                       \
      acc[_i][_j] = __builtin_amdgcn_mfma_f32_16x16x32_bf16(                 \
          a[_i][0], b[_j][0], acc[_i][_j], 0, 0, 0);                         \
      acc[_i][_j] = __builtin_amdgcn_mfma_f32_16x16x32_bf16(                 \
          a[_i][1], b[_j][1], acc[_i][_j], 0, 0, 0);                         \
    }                                                                        \
  } while (0)

  constexpr int NT = KD / 64;

  // prologue: stage tile 0 (4 loads)
  STAGE_A2(0, 0);
  STAGE_B2(0, 0);

  int c = 0;
  for (int tk = 1; tk < NT; ++tk) {
    const int kn = tk * 64;
    const int d = c ^ 1;
    STAGE_A2(d, kn);            // outstanding 4 -> 6
    WAIT_VM(2);                 // retire exactly the previous tile's 4 loads
    BARRIER;
    LOAD_A2(c);
    LOAD_B2(c);
    STAGE_B2(d, kn);            // issue B after the wait: 2 -> 4
    __builtin_amdgcn_s_setprio(1);
    MMA2;
    __builtin_amdgcn_s_setprio(0);
    BARRIER;                    // WAR before next iter writes buf c
    c = d;
  }

  WAIT_VM(0);
  BARRIER;
  LOAD_A2(c);
  LOAD_B2(c);
  MMA2;

  // epilogue: scatter rows via row_dst, +bias +pos_emb +seq_emb (f32 out)
#pragma unroll
  for (int i = 0; i < 2; ++i) {
    int mbase = m0 + wm * 32 + i * 16 + l4 * 4;     // local row
#pragma unroll
    for (int q = 0; q < 4; ++q) {
      int r = mbase + q;                            // local row
      if (row_base + r >= M) continue;
      int dst = row_dst[row_base + r];              // (b*S+s)*L + slot
      int slot = dst & (NL - 1);
      int sg = (dst >> 8) & 3;
#pragma unroll
      for (int j = 0; j < 4; ++j) {
        int n = n0 + wn * 64 + j * 16 + l15;
        float v = acc[i][j][q] + bias[n] + pos_emb[slot * ND + n] +
                  seq_emb[(sg + 1) * ND + n];
        out[(size_t)dst * ND + n] = v;              // f32 output
      }
    }
  }
#undef STAGE_A2
#undef STAGE_B2
#undef LOAD_A2
#undef LOAD_B2
#undef MMA2
}

// ---------------------------------------------------------------------------
extern "C" void kernel_launch(void* const* d_in, const int* in_sizes, int n_in,
                              void* d_out, int out_size, void* d_ws,
                              size_t ws_size, hipStream_t stream) {
  const float* embed_table = (const float*)d_in[0];
  const float* time_gap_emb = (const float*)d_in[1];
  const float* seq_id_emb = (const float*)d_in[2];
  const float* pos_emb = (const float*)d_in[3];
  const float* ln_gamma = (const float*)d_in[4];
  const float* ln_beta = (const float*)d_in[5];
  const float* w1 = (const float*)d_in[6];
  const float* b1 = (const float*)d_in[7];
  const float* w2 = (const float*)d_in[8];
  const float* b2 = (const float*)d_in[9];
  const float* empty_tokens = (const float*)d_in[10];
  const int* history_tokens = (const int*)d_in[11];
  const int* post_tokens = (const int*)d_in[12];
  const int* author_tokens = (const int*)d_in[13];
  const int* action_tokens = (const int*)d_in[14];
  const int* time_gap = (const int*)d_in[15];
  const int* group_ids = (const int*)d_in[16];
  const int* lengths = (const int*)d_in[17];

  // Runtime-adaptive chunking.  ws_size is constant across calls/replays, so
  // this branch is identical on every invocation (graph-capture safe).
  const size_t fixed = 266240 + (size_t)(HID * FIVE_D + ND * HID) * 2;
  int chunk, nchunk;
  if (ws_size >= fixed + (size_t)32768 * 9216) { chunk = 32768; nchunk = 1; }
  else if (ws_size >= fixed + (size_t)16384 * 9216) { chunk = 16384; nchunk = 2; }
  else { chunk = 8192; nchunk = 4; }

  char* ws = (char*)d_ws;
  int* n_rows = (int*)ws;                                  // 4 B
  int* row_src = (int*)(ws + 4096);                        // 32768*4 B
  int* row_dst = (int*)(ws + 4096 + 131072);               // 32768*4 B
  bf16_t* W1T = (bf16_t*)(ws + 266240);                    // [2048][2560] bf16
  bf16_t* W2T = W1T + (size_t)HID * FIVE_D;                // [512][2048]  bf16
  bf16_t* Xc = W2T + (size_t)ND * HID;                     // [chunk][2560] bf16
  bf16_t* H1c = Xc + (size_t)chunk * FIVE_D;               // [chunk][2048] bf16

  float* out_states = (float*)d_out;                       // f32 output
  float* out_mask = out_states + (size_t)NB * NS * NL * ND;

  // Dynamic-LDS opt-in for the two GEMMs (host-side, idempotent).
  (void)hipFuncSetAttribute(
      reinterpret_cast<const void*>(gemm256_kernel<FIVE_D, HID>),
      hipFuncAttributeMaxDynamicSharedMemorySize, 131072);
  (void)hipFuncSetAttribute(
      reinterpret_cast<const void*>(gemm128_scatter_kernel<HID>),
      hipFuncAttributeMaxDynamicSharedMemorySize, 65536);

  // n_rows must start at 0 (ws is poisoned 0xAA before every launch).
  hipMemsetAsync(n_rows, 0, 4, stream);

  build_index_kernel<<<NB * NS * 4, 256, 0, stream>>>(
      group_ids, lengths, n_rows, row_src, row_dst, empty_tokens, pos_emb,
      seq_id_emb, out_states, out_mask);

  transpose_cvt_kernel<FIVE_D, HID>
      <<<dim3(HID / 32, FIVE_D / 32), 256, 0, stream>>>(w1, W1T);
  transpose_cvt_kernel<HID, ND>
      <<<dim3(ND / 32, HID / 32), 256, 0, stream>>>(w2, W2T);

  for (int c = 0; c < nchunk; ++c) {
    int row_base = c * chunk;
    gather_ln_kernel<<<2048, 256, 0, stream>>>(
        embed_table, time_gap_emb, history_tokens, post_tokens, author_tokens,
        action_tokens, time_gap, ln_gamma, ln_beta, n_rows, row_src, row_base,
        chunk, Xc);

    gemm256_kernel<FIVE_D, HID>
        <<<dim3(chunk / 256, HID / 256), 512, 131072, stream>>>(
            Xc, W1T, n_rows, row_base, b1, H1c);

    gemm128_scatter_kernel<HID>
        <<<dim3(chunk / 128, ND / 128), 512, 65536, stream>>>(
            H1c, W2T, n_rows, row_base, b2, row_dst, pos_emb, seq_id_emb,
            out_states);
  }
}

// Round 10
// 394.498 us; speedup vs baseline: 1.1587x; 1.0032x over previous
//
#include <hip/hip_runtime.h>
#include <hip/hip_bf16.h>
#include <stdint.h>

// Problem constants
#define NB 32
#define NL 256
#define NS 4
#define ND 512
#define NH 1024           // NL * NS
#define FIVE_D 2560
#define HID 2048
#define MMAX 32768        // NB * NS * NL (cap on compact rows)

// Inputs: f32 / int32. OUTPUT: f32 (states [B,S,L,D] then mask [B,S,L]).
typedef __bf16 bf16_t;
typedef __bf16 bf16x4 __attribute__((ext_vector_type(4)));
typedef __bf16 bf16x8 __attribute__((ext_vector_type(8)));
typedef float f32x4 __attribute__((ext_vector_type(4)));

// async global->LDS, 16B per lane (wave-uniform base + lane*16 layout).
__device__ __forceinline__ void async_ld16(const void* g, void* l) {
  __builtin_amdgcn_global_load_lds(
      (__attribute__((address_space(1))) void*)(uintptr_t)g,
      (__attribute__((address_space(3))) void*)(uintptr_t)l, 16, 0, 0);
}

// ---------------------------------------------------------------------------
// K1: build compact row index + background fill + mask (4 blocks/group).
// ---------------------------------------------------------------------------
__global__ void build_index_kernel(const int* __restrict__ group_ids,
                                   const int* __restrict__ lengths,
                                   int* __restrict__ n_rows,
                                   int* __restrict__ row_src,
                                   int* __restrict__ row_dst,
                                   const float* __restrict__ empty_tokens,
                                   const float* __restrict__ pos_emb,
                                   const float* __restrict__ seq_emb,
                                   float* __restrict__ out,
                                   float* __restrict__ mask) {
  const int g = blockIdx.x >> 2;       // group: b*NS + s
  const int qtr = blockIdx.x & 3;      // fill quarter
  const int b = g >> 2, s = g & 3;
  const int t = threadIdx.x;           // 0..255
  const int lane = t & 63, w = t >> 6; // 4 waves
  int len = lengths[b];
  len = len < 0 ? 0 : (len > NH ? NH : len);
  const int* gi = group_ids + b * NH;

  __shared__ int wtot[16];             // per (chunk, wave) match counts
  __shared__ int sbase;

  bool valid[4];
#pragma unroll
  for (int c = 0; c < 4; ++c) {
    int h = c * 256 + t;
    valid[c] = (h < len) && (gi[h] == s + 1);
    unsigned long long m = __ballot(valid[c]);
    if (lane == 0) wtot[c * 4 + w] = __popcll(m);
  }
  __syncthreads();

  int pre[16];
  int run = 0;
#pragma unroll
  for (int i = 0; i < 16; ++i) { pre[i] = run; run += wtot[i]; }
  const int count = run;
  const int keff = count < NL ? count : NL;
  const int offset = count - keff;     // max(count - L, 0)

  const bool empty = (count == 0);
  const int start = empty ? 1 : keff;

  if (qtr == 0) {
    if (t == 0) sbase = atomicAdd(n_rows, keff);
    __syncthreads();
    const int base = sbase;

    const unsigned long long lt = (1ull << lane) - 1ull;
#pragma unroll
    for (int c = 0; c < 4; ++c) {
      unsigned long long m = __ballot(valid[c]);
      if (valid[c]) {
        int rank = pre[c * 4 + w] + __popcll(m & lt);
        if (rank >= offset) {
          int slot = rank - offset;
          row_src[base + slot] = b * NH + c * 256 + t;
          row_dst[base + slot] = g * NL + slot;
        }
      }
    }

    const int keptm = empty ? 1 : keff;
    mask[g * NL + t] = (t < keptm) ? 1.f : 0.f;    // t in [0,256)=L

    if (empty) {
      float* basep = out + (size_t)g * NL * ND;
      for (int d = t; d < ND; d += 256)
        basep[d] = empty_tokens[s * ND + d] + pos_emb[d] +
                   seq_emb[(s + 1) * ND + d];
    }
  }

  // zero-fill: this quarter covers slots [qtr*64, qtr*64+64) clamped to
  // [start, 256).  One slot = 128 uint4.
  int lo = qtr * 64; if (lo < start) lo = start;
  const int hi = qtr * 64 + 64;
  if (lo < hi) {
    uint4* p = (uint4*)(out + (size_t)g * NL * ND);
    uint4 z; z.x = z.y = z.z = z.w = 0u;
    for (int i = lo * (ND / 4) + t; i < hi * (ND / 4); i += 256) p[i] = z;
  }
}

// ---------------------------------------------------------------------------
// K2: f32 [K,N] -> bf16 [N,K] tiled transpose (weights).
// ---------------------------------------------------------------------------
template <int KD, int NDIM>
__global__ void transpose_cvt_kernel(const float* __restrict__ src,
                                     bf16_t* __restrict__ dst) {
  __shared__ float tile[32][33];
  int k0 = blockIdx.y * 32, n0 = blockIdx.x * 32;
  int tx = threadIdx.x & 31, ty = threadIdx.x >> 5;   // 32 x 8
#pragma unroll
  for (int i = 0; i < 32; i += 8)
    tile[ty + i][tx] = src[(size_t)(k0 + ty + i) * NDIM + n0 + tx];
  __syncthreads();
#pragma unroll
  for (int i = 0; i < 32; i += 8)
    dst[(size_t)(n0 + ty + i) * KD + k0 + tx] = (bf16_t)tile[tx][ty + i];
}

// ---------------------------------------------------------------------------
// K3: gather 5 f32 embeddings + LayerNorm -> bf16 X[r_local, 2560]
// Wave-per-row, rule-#20-clean: 10 named float4 loads with literal
// seg/offset, no LDS, no syncs, 64-lane butterfly reduce.  (verified r9)
// ---------------------------------------------------------------------------
__launch_bounds__(256)
__global__ void gather_ln_kernel(const float* __restrict__ embed,
                                 const float* __restrict__ tg_emb,
                                 const int* __restrict__ ht,
                                 const int* __restrict__ pt,
                                 const int* __restrict__ at,
                                 const int* __restrict__ ct,
                                 const int* __restrict__ tg,
                                 const float* __restrict__ gamma,
                                 const float* __restrict__ beta,
                                 const int* __restrict__ n_rows,
                                 const int* __restrict__ row_src,
                                 int row_base, int chunk,
                                 bf16_t* __restrict__ X) {
  const int l = threadIdx.x & 63;              // lane
  const int wid = blockIdx.x * 4 + (threadIdx.x >> 6);
  const int wstride = gridDim.x * 4;
  const int M = *n_rows;
  int lim = row_base + chunk;
  if (lim > M) lim = M;

  const int o = l * 4;                         // float offset within 256-span

  for (int r = row_base + wid; r < lim; r += wstride) {
    const int rl = r - row_base;
    const int pos = row_src[r];

    const float* s0 = embed + (size_t)ht[pos] * ND;
    const float* s1 = embed + (size_t)pt[pos] * ND;
    const float* s2 = embed + (size_t)at[pos] * ND;
    const float* s3 = embed + (size_t)ct[pos] * ND;
    int tgv = tg[pos];
    tgv = tgv < 0 ? 0 : (tgv > 128 ? 128 : tgv);
    const float* s4 = tg_emb + (size_t)tgv * ND;

    // 10 independent 16B loads, named, literal seg/offset.
    float4 v0 = *(const float4*)(s0 + o);
    float4 v1 = *(const float4*)(s0 + 256 + o);
    float4 v2 = *(const float4*)(s1 + o);
    float4 v3 = *(const float4*)(s1 + 256 + o);
    float4 v4 = *(const float4*)(s2 + o);
    float4 v5 = *(const float4*)(s2 + 256 + o);
    float4 v6 = *(const float4*)(s3 + o);
    float4 v7 = *(const float4*)(s3 + 256 + o);
    float4 v8 = *(const float4*)(s4 + o);
    float4 v9 = *(const float4*)(s4 + 256 + o);

    float sum = 0.f, sq = 0.f;
#define ACC(vk)                                                              \
    do {                                                                     \
      sum += vk.x + vk.y + vk.z + vk.w;                                      \
      sq += vk.x * vk.x + vk.y * vk.y + vk.z * vk.z + vk.w * vk.w;           \
    } while (0)
    ACC(v0); ACC(v1); ACC(v2); ACC(v3); ACC(v4);
    ACC(v5); ACC(v6); ACC(v7); ACC(v8); ACC(v9);
#undef ACC
#pragma unroll
    for (int off = 32; off > 0; off >>= 1) {
      sum += __shfl_xor(sum, off);
      sq += __shfl_xor(sq, off);
    }
    const float mu = sum * (1.f / FIVE_D);
    const float var = sq * (1.f / FIVE_D) - mu * mu;
    const float rstd = rsqrtf(var + 1e-5f);

    bf16_t* xr = X + (size_t)rl * FIVE_D;
#define LN_STORE(vk, kofs)                                                   \
    do {                                                                     \
      float4 gm = *(const float4*)(gamma + (kofs) + o);                      \
      float4 bt = *(const float4*)(beta + (kofs) + o);                       \
      bf16x4 ov;                                                             \
      ov[0] = (bf16_t)((vk.x - mu) * rstd * gm.x + bt.x);                    \
      ov[1] = (bf16_t)((vk.y - mu) * rstd * gm.y + bt.y);                    \
      ov[2] = (bf16_t)((vk.z - mu) * rstd * gm.z + bt.z);                    \
      ov[3] = (bf16_t)((vk.w - mu) * rstd * gm.w + bt.w);                    \
      *(bf16x4*)(xr + (kofs) + o) = ov;                                      \
    } while (0)
    LN_STORE(v0, 0);    LN_STORE(v1, 256);
    LN_STORE(v2, 512);  LN_STORE(v3, 768);
    LN_STORE(v4, 1024); LN_STORE(v5, 1280);
    LN_STORE(v6, 1536); LN_STORE(v7, 1792);
    LN_STORE(v8, 2048); LN_STORE(v9, 2304);
#undef LN_STORE
  }
}

// ---------------------------------------------------------------------------
// Shared sync macros.  v4 ledger (verified): one counted wait per K-tile
// covering the ENTIRE previous-staged tile; A-stage ahead of the wait,
// B-stage right AFTER the wait.  vmcnt never reaches 0 in the main loop.
// ---------------------------------------------------------------------------
#define FENCE asm volatile("" ::: "memory")
#define BARRIER do { FENCE; __builtin_amdgcn_s_barrier(); FENCE; } while (0)
#define WAIT_VM(n) asm volatile("s_waitcnt vmcnt(" #n ")" ::: "memory")

// ---------------------------------------------------------------------------
// K4: 128x128 MFMA GEMM, v4 counted-vmcnt ledger, BOTH GEMMs.
// ROUND-10: gemm256 (1 block/CU, J=520 jobs on 256 slots -> 3-round
// makespan, 33% tail waste) is replaced by this 128^2 kernel for GEMM1 too.
// Rationale (r8/r9 post-mortems): per-wave acc is only 32 VGPRs here, total
// ~110-120 <= 128, so __launch_bounds__(512,4) gives 4 waves/SIMD ->
// TWO 512-thread blocks per CU (LDS 2x64 KiB = 128 <= 160): (a) co-resident
// blocks overlap each other's WAIT_VM stalls (the TLP 256^2 could not have);
// (b) J = 2064 fine jobs -> imbalance tail ~7 us instead of ~50.
// blockIdx.x = M-panel (fast axis): same-A siblings strided gridDim.x,
// 256 % 8 == 0 -> same XCD (T1, r8-verified FETCH = compulsory).
// EPI=1: bias+SiLU -> bf16 Cb[.,LDC].  EPI=2: +bias+pos+seq scatter f32.
// 512 thr = 8 waves (4M x 2N), per-wave 32x64 output, BK=64, 64 KiB LDS.
// ---------------------------------------------------------------------------
template <int KD, int LDC, int EPI>
__launch_bounds__(512, 4)
__global__ void gemm128_kernel(const bf16_t* __restrict__ A,
                               const bf16_t* __restrict__ Bt,
                               const int* __restrict__ nrows_p,
                               int row_base,
                               const float* __restrict__ bias,
                               bf16_t* __restrict__ Cb,
                               const int* __restrict__ row_dst,
                               const float* __restrict__ pos_emb,
                               const float* __restrict__ seq_emb,
                               float* __restrict__ out) {
  static_assert(KD % 64 == 0 && KD / 64 >= 2, "KD");
  const int M = *nrows_p;
  const int m0 = blockIdx.x * 128;       // M-panel on x (fast axis)
  if (row_base + m0 >= M) return;
  const int n0 = blockIdx.y * 128;       // N-panel on y

  extern __shared__ char smem[];   // [2][ A 16KB | B 16KB ] = 64 KiB

  const int t = threadIdx.x;        // 0..511
  const int lane = t & 63;
  const int wv = t >> 6;            // 0..7
  const int wm = wv >> 1;           // 0..3  (M quarter, 32 rows)
  const int wn = wv & 1;            // 0..1  (N half, 64 cols)
  const int l15 = lane & 15;
  const int l4 = lane >> 4;

  const int r0 = t >> 3;               // 0..63
  const int sq = (t & 7) ^ (r0 & 7);
  const bf16_t* Ab = A + (size_t)(m0 + r0) * KD + sq * 8;
  const bf16_t* Bb = Bt + (size_t)(n0 + r0) * KD + sq * 8;
  const int dst16 = t * 16;

  const int cs0 = (l4 ^ (l15 & 7)) << 4;   // ks=0 swizzled byte slot
  const int cs1 = cs0 ^ 64;                // ks=1
  const int arow = (wm * 32 + l15) * 128;  // A row byte base for this wave
  const int brow = (wn * 64 + l15) * 128;  // B row byte base

  f32x4 acc[2][4] = {};                    // [i (16-row frag)][j (16-col frag)]
  bf16x8 a[2][2], b[4][2];

#define STAGE_A2(dbuf, kofs)                                                 \
  do {                                                                       \
    char* _d = smem + (dbuf) * 32768 + dst16;                                \
    async_ld16(Ab + (kofs), _d);                                             \
    async_ld16(Ab + (size_t)64 * KD + (kofs), _d + 8192);                    \
  } while (0)
#define STAGE_B2(dbuf, kofs)                                                 \
  do {                                                                       \
    char* _d = smem + (dbuf) * 32768 + 16384 + dst16;                        \
    async_ld16(Bb + (kofs), _d);                                             \
    async_ld16(Bb + (size_t)64 * KD + (kofs), _d + 8192);                    \
  } while (0)
#define LOAD_A2(cbuf)                                                        \
  do {                                                                       \
    const char* _s = smem + (cbuf) * 32768 + arow;                           \
    _Pragma("unroll") for (int _i = 0; _i < 2; ++_i) {                       \
      a[_i][0] = *(const bf16x8*)(_s + _i * 2048 + cs0);                     \
      a[_i][1] = *(const bf16x8*)(_s + _i * 2048 + cs1);                     \
    }                                                                        \
  } while (0)
#define LOAD_B2(cbuf)                                                        \
  do {                                                                       \
    const char* _s = smem + (cbuf) * 32768 + 16384 + brow;                   \
    _Pragma("unroll") for (int _j = 0; _j < 4; ++_j) {                       \
      b[_j][0] = *(const bf16x8*)(_s + _j * 2048 + cs0);                     \
      b[_j][1] = *(const bf16x8*)(_s + _j * 2048 + cs1);                     \
    }                                                                        \
  } while (0)
#define MMA2                                                                 \
  do {                                                                       \
    _Pragma("unroll") for (int _i = 0; _i < 2; ++_i)                         \
    _Pragma("unroll") for (int _j = 0; _j < 4; ++_j) {                       \
      acc[_i][_j] = __builtin_amdgcn_mfma_f32_16x16x32_bf16(                 \
          a[_i][0], b[_j][0], acc[_i][_j], 0, 0, 0);                         \
      acc[_i][_j] = __builtin_amdgcn_mfma_f32_16x16x32_bf16(                 \
          a[_i][1], b[_j][1], acc[_i][_j], 0, 0, 0);                         \
    }                                                                        \
  } while (0)

  constexpr int NT = KD / 64;

  // prologue: stage tile 0 (4 loads)
  STAGE_A2(0, 0);
  STAGE_B2(0, 0);

  int c = 0;
  for (int tk = 1; tk < NT; ++tk) {
    const int kn = tk * 64;
    const int d = c ^ 1;
    STAGE_A2(d, kn);            // outstanding 4 -> 6
    WAIT_VM(2);                 // retire exactly the previous tile's 4 loads
    BARRIER;
    LOAD_A2(c);
    LOAD_B2(c);
    STAGE_B2(d, kn);            // issue B after the wait: 2 -> 4
    __builtin_amdgcn_s_setprio(1);
    MMA2;
    __builtin_amdgcn_s_setprio(0);
    BARRIER;                    // WAR before next iter writes buf c
    c = d;
  }

  WAIT_VM(0);
  BARRIER;
  LOAD_A2(c);
  LOAD_B2(c);
  MMA2;

  if constexpr (EPI == 1) {
    // bias + SiLU -> bf16 (rows beyond M are garbage; GEMM2 guards)
#pragma unroll
    for (int i = 0; i < 2; ++i) {
      int mbase = m0 + wm * 32 + i * 16 + l4 * 4;   // local row
#pragma unroll
      for (int j = 0; j < 4; ++j) {
        int n = n0 + wn * 64 + j * 16 + l15;
        float bn = bias[n];
#pragma unroll
        for (int q = 0; q < 4; ++q) {
          float v = acc[i][j][q] + bn;
          v = v / (1.f + __expf(-v));              // SiLU
          Cb[(size_t)(mbase + q) * LDC + n] = (bf16_t)v;
        }
      }
    }
  } else {
    // scatter rows via row_dst, +bias +pos_emb +seq_emb (f32 out)
#pragma unroll
    for (int i = 0; i < 2; ++i) {
      int mbase = m0 + wm * 32 + i * 16 + l4 * 4;   // local row
#pragma unroll
      for (int q = 0; q < 4; ++q) {
        int r = mbase + q;                          // local row
        if (row_base + r >= M) continue;
        int dst = row_dst[row_base + r];            // (b*S+s)*L + slot
        int slot = dst & (NL - 1);
        int sg = (dst >> 8) & 3;
#pragma unroll
        for (int j = 0; j < 4; ++j) {
          int n = n0 + wn * 64 + j * 16 + l15;
          float v = acc[i][j][q] + bias[n] + pos_emb[slot * ND + n] +
                    seq_emb[(sg + 1) * ND + n];
          out[(size_t)dst * ND + n] = v;            // f32 output
        }
      }
    }
  }
#undef STAGE_A2
#undef STAGE_B2
#undef LOAD_A2
#undef LOAD_B2
#undef MMA2
}

// ---------------------------------------------------------------------------
extern "C" void kernel_launch(void* const* d_in, const int* in_sizes, int n_in,
                              void* d_out, int out_size, void* d_ws,
                              size_t ws_size, hipStream_t stream) {
  const float* embed_table = (const float*)d_in[0];
  const float* time_gap_emb = (const float*)d_in[1];
  const float* seq_id_emb = (const float*)d_in[2];
  const float* pos_emb = (const float*)d_in[3];
  const float* ln_gamma = (const float*)d_in[4];
  const float* ln_beta = (const float*)d_in[5];
  const float* w1 = (const float*)d_in[6];
  const float* b1 = (const float*)d_in[7];
  const float* w2 = (const float*)d_in[8];
  const float* b2 = (const float*)d_in[9];
  const float* empty_tokens = (const float*)d_in[10];
  const int* history_tokens = (const int*)d_in[11];
  const int* post_tokens = (const int*)d_in[12];
  const int* author_tokens = (const int*)d_in[13];
  const int* action_tokens = (const int*)d_in[14];
  const int* time_gap = (const int*)d_in[15];
  const int* group_ids = (const int*)d_in[16];
  const int* lengths = (const int*)d_in[17];

  // Runtime-adaptive chunking.  ws_size is constant across calls/replays, so
  // this branch is identical on every invocation (graph-capture safe).
  const size_t fixed = 266240 + (size_t)(HID * FIVE_D + ND * HID) * 2;
  int chunk, nchunk;
  if (ws_size >= fixed + (size_t)32768 * 9216) { chunk = 32768; nchunk = 1; }
  else if (ws_size >= fixed + (size_t)16384 * 9216) { chunk = 16384; nchunk = 2; }
  else { chunk = 8192; nchunk = 4; }

  char* ws = (char*)d_ws;
  int* n_rows = (int*)ws;                                  // 4 B
  int* row_src = (int*)(ws + 4096);                        // 32768*4 B
  int* row_dst = (int*)(ws + 4096 + 131072);               // 32768*4 B
  bf16_t* W1T = (bf16_t*)(ws + 266240);                    // [2048][2560] bf16
  bf16_t* W2T = W1T + (size_t)HID * FIVE_D;                // [512][2048]  bf16
  bf16_t* Xc = W2T + (size_t)ND * HID;                     // [chunk][2560] bf16
  bf16_t* H1c = Xc + (size_t)chunk * FIVE_D;               // [chunk][2048] bf16

  float* out_states = (float*)d_out;                       // f32 output
  float* out_mask = out_states + (size_t)NB * NS * NL * ND;

  // Dynamic-LDS opt-in for both GEMM instantiations (host-side, idempotent).
  (void)hipFuncSetAttribute(
      reinterpret_cast<const void*>(gemm128_kernel<FIVE_D, HID, 1>),
      hipFuncAttributeMaxDynamicSharedMemorySize, 65536);
  (void)hipFuncSetAttribute(
      reinterpret_cast<const void*>(gemm128_kernel<HID, ND, 2>),
      hipFuncAttributeMaxDynamicSharedMemorySize, 65536);

  // n_rows must start at 0 (ws is poisoned 0xAA before every launch).
  hipMemsetAsync(n_rows, 0, 4, stream);

  build_index_kernel<<<NB * NS * 4, 256, 0, stream>>>(
      group_ids, lengths, n_rows, row_src, row_dst, empty_tokens, pos_emb,
      seq_id_emb, out_states, out_mask);

  transpose_cvt_kernel<FIVE_D, HID>
      <<<dim3(HID / 32, FIVE_D / 32), 256, 0, stream>>>(w1, W1T);
  transpose_cvt_kernel<HID, ND>
      <<<dim3(ND / 32, HID / 32), 256, 0, stream>>>(w2, W2T);

  for (int c = 0; c < nchunk; ++c) {
    int row_base = c * chunk;
    gather_ln_kernel<<<2048, 256, 0, stream>>>(
        embed_table, time_gap_emb, history_tokens, post_tokens, author_tokens,
        action_tokens, time_gap, ln_gamma, ln_beta, n_rows, row_src, row_base,
        chunk, Xc);

    gemm128_kernel<FIVE_D, HID, 1>
        <<<dim3(chunk / 128, HID / 128), 512, 65536, stream>>>(
            Xc, W1T, n_rows, row_base, b1, H1c, nullptr, nullptr, nullptr,
            nullptr);

    gemm128_kernel<HID, ND, 2>
        <<<dim3(chunk / 128, ND / 128), 512, 65536, stream>>>(
            H1c, W2T, n_rows, row_base, b2, nullptr, row_dst, pos_emb,
            seq_id_emb, out_states);
  }
}

// Round 11
// 389.873 us; speedup vs baseline: 1.1724x; 1.0119x over previous
//
#include <hip/hip_runtime.h>
#include <hip/hip_bf16.h>
#include <stdint.h>

// Problem constants
#define NB 32
#define NL 256
#define NS 4
#define ND 512
#define NH 1024           // NL * NS
#define FIVE_D 2560
#define HID 2048
#define MMAX 32768        // NB * NS * NL (cap on compact rows)

// Inputs: f32 / int32. OUTPUT: f32 (states [B,S,L,D] then mask [B,S,L]).
typedef __bf16 bf16_t;
typedef __bf16 bf16x4 __attribute__((ext_vector_type(4)));
typedef __bf16 bf16x8 __attribute__((ext_vector_type(8)));
typedef float f32x4 __attribute__((ext_vector_type(4)));

// async global->LDS, 16B per lane (wave-uniform base + lane*16 layout).
__device__ __forceinline__ void async_ld16(const void* g, void* l) {
  __builtin_amdgcn_global_load_lds(
      (__attribute__((address_space(1))) void*)(uintptr_t)g,
      (__attribute__((address_space(3))) void*)(uintptr_t)l, 16, 0, 0);
}

// ---------------------------------------------------------------------------
// K1: build compact row index + background fill + mask (4 blocks/group).
// ---------------------------------------------------------------------------
__global__ void build_index_kernel(const int* __restrict__ group_ids,
                                   const int* __restrict__ lengths,
                                   int* __restrict__ n_rows,
                                   int* __restrict__ row_src,
                                   int* __restrict__ row_dst,
                                   const float* __restrict__ empty_tokens,
                                   const float* __restrict__ pos_emb,
                                   const float* __restrict__ seq_emb,
                                   float* __restrict__ out,
                                   float* __restrict__ mask) {
  const int g = blockIdx.x >> 2;       // group: b*NS + s
  const int qtr = blockIdx.x & 3;      // fill quarter
  const int b = g >> 2, s = g & 3;
  const int t = threadIdx.x;           // 0..255
  const int lane = t & 63, w = t >> 6; // 4 waves
  int len = lengths[b];
  len = len < 0 ? 0 : (len > NH ? NH : len);
  const int* gi = group_ids + b * NH;

  __shared__ int wtot[16];             // per (chunk, wave) match counts
  __shared__ int sbase;

  bool valid[4];
#pragma unroll
  for (int c = 0; c < 4; ++c) {
    int h = c * 256 + t;
    valid[c] = (h < len) && (gi[h] == s + 1);
    unsigned long long m = __ballot(valid[c]);
    if (lane == 0) wtot[c * 4 + w] = __popcll(m);
  }
  __syncthreads();

  int pre[16];
  int run = 0;
#pragma unroll
  for (int i = 0; i < 16; ++i) { pre[i] = run; run += wtot[i]; }
  const int count = run;
  const int keff = count < NL ? count : NL;
  const int offset = count - keff;     // max(count - L, 0)

  const bool empty = (count == 0);
  const int start = empty ? 1 : keff;

  if (qtr == 0) {
    if (t == 0) sbase = atomicAdd(n_rows, keff);
    __syncthreads();
    const int base = sbase;

    const unsigned long long lt = (1ull << lane) - 1ull;
#pragma unroll
    for (int c = 0; c < 4; ++c) {
      unsigned long long m = __ballot(valid[c]);
      if (valid[c]) {
        int rank = pre[c * 4 + w] + __popcll(m & lt);
        if (rank >= offset) {
          int slot = rank - offset;
          row_src[base + slot] = b * NH + c * 256 + t;
          row_dst[base + slot] = g * NL + slot;
        }
      }
    }

    const int keptm = empty ? 1 : keff;
    mask[g * NL + t] = (t < keptm) ? 1.f : 0.f;    // t in [0,256)=L

    if (empty) {
      float* basep = out + (size_t)g * NL * ND;
      for (int d = t; d < ND; d += 256)
        basep[d] = empty_tokens[s * ND + d] + pos_emb[d] +
                   seq_emb[(s + 1) * ND + d];
    }
  }

  // zero-fill: this quarter covers slots [qtr*64, qtr*64+64) clamped to
  // [start, 256).  One slot = 128 uint4.
  int lo = qtr * 64; if (lo < start) lo = start;
  const int hi = qtr * 64 + 64;
  if (lo < hi) {
    uint4* p = (uint4*)(out + (size_t)g * NL * ND);
    uint4 z; z.x = z.y = z.z = z.w = 0u;
    for (int i = lo * (ND / 4) + t; i < hi * (ND / 4); i += 256) p[i] = z;
  }
}

// ---------------------------------------------------------------------------
// K2: f32 [K,N] -> bf16 [N,K] tiled transpose (weights).
// ---------------------------------------------------------------------------
template <int KD, int NDIM>
__global__ void transpose_cvt_kernel(const float* __restrict__ src,
                                     bf16_t* __restrict__ dst) {
  __shared__ float tile[32][33];
  int k0 = blockIdx.y * 32, n0 = blockIdx.x * 32;
  int tx = threadIdx.x & 31, ty = threadIdx.x >> 5;   // 32 x 8
#pragma unroll
  for (int i = 0; i < 32; i += 8)
    tile[ty + i][tx] = src[(size_t)(k0 + ty + i) * NDIM + n0 + tx];
  __syncthreads();
#pragma unroll
  for (int i = 0; i < 32; i += 8)
    dst[(size_t)(n0 + ty + i) * KD + k0 + tx] = (bf16_t)tile[tx][ty + i];
}

// ---------------------------------------------------------------------------
// K3: gather 5 f32 embeddings + LayerNorm -> bf16 X[r_local, 2560]
// Wave-per-row, rule-#20-clean: 10 named float4 loads with literal
// seg/offset, no LDS, no syncs, 64-lane butterfly reduce.  (verified r9)
// ---------------------------------------------------------------------------
__launch_bounds__(256)
__global__ void gather_ln_kernel(const float* __restrict__ embed,
                                 const float* __restrict__ tg_emb,
                                 const int* __restrict__ ht,
                                 const int* __restrict__ pt,
                                 const int* __restrict__ at,
                                 const int* __restrict__ ct,
                                 const int* __restrict__ tg,
                                 const float* __restrict__ gamma,
                                 const float* __restrict__ beta,
                                 const int* __restrict__ n_rows,
                                 const int* __restrict__ row_src,
                                 int row_base, int chunk,
                                 bf16_t* __restrict__ X) {
  const int l = threadIdx.x & 63;              // lane
  const int wid = blockIdx.x * 4 + (threadIdx.x >> 6);
  const int wstride = gridDim.x * 4;
  const int M = *n_rows;
  int lim = row_base + chunk;
  if (lim > M) lim = M;

  const int o = l * 4;                         // float offset within 256-span

  for (int r = row_base + wid; r < lim; r += wstride) {
    const int rl = r - row_base;
    const int pos = row_src[r];

    const float* s0 = embed + (size_t)ht[pos] * ND;
    const float* s1 = embed + (size_t)pt[pos] * ND;
    const float* s2 = embed + (size_t)at[pos] * ND;
    const float* s3 = embed + (size_t)ct[pos] * ND;
    int tgv = tg[pos];
    tgv = tgv < 0 ? 0 : (tgv > 128 ? 128 : tgv);
    const float* s4 = tg_emb + (size_t)tgv * ND;

    // 10 independent 16B loads, named, literal seg/offset.
    float4 v0 = *(const float4*)(s0 + o);
    float4 v1 = *(const float4*)(s0 + 256 + o);
    float4 v2 = *(const float4*)(s1 + o);
    float4 v3 = *(const float4*)(s1 + 256 + o);
    float4 v4 = *(const float4*)(s2 + o);
    float4 v5 = *(const float4*)(s2 + 256 + o);
    float4 v6 = *(const float4*)(s3 + o);
    float4 v7 = *(const float4*)(s3 + 256 + o);
    float4 v8 = *(const float4*)(s4 + o);
    float4 v9 = *(const float4*)(s4 + 256 + o);

    float sum = 0.f, sq = 0.f;
#define ACC(vk)                                                              \
    do {                                                                     \
      sum += vk.x + vk.y + vk.z + vk.w;                                      \
      sq += vk.x * vk.x + vk.y * vk.y + vk.z * vk.z + vk.w * vk.w;           \
    } while (0)
    ACC(v0); ACC(v1); ACC(v2); ACC(v3); ACC(v4);
    ACC(v5); ACC(v6); ACC(v7); ACC(v8); ACC(v9);
#undef ACC
#pragma unroll
    for (int off = 32; off > 0; off >>= 1) {
      sum += __shfl_xor(sum, off);
      sq += __shfl_xor(sq, off);
    }
    const float mu = sum * (1.f / FIVE_D);
    const float var = sq * (1.f / FIVE_D) - mu * mu;
    const float rstd = rsqrtf(var + 1e-5f);

    bf16_t* xr = X + (size_t)rl * FIVE_D;
#define LN_STORE(vk, kofs)                                                   \
    do {                                                                     \
      float4 gm = *(const float4*)(gamma + (kofs) + o);                      \
      float4 bt = *(const float4*)(beta + (kofs) + o);                       \
      bf16x4 ov;                                                             \
      ov[0] = (bf16_t)((vk.x - mu) * rstd * gm.x + bt.x);                    \
      ov[1] = (bf16_t)((vk.y - mu) * rstd * gm.y + bt.y);                    \
      ov[2] = (bf16_t)((vk.z - mu) * rstd * gm.z + bt.z);                    \
      ov[3] = (bf16_t)((vk.w - mu) * rstd * gm.w + bt.w);                    \
      *(bf16x4*)(xr + (kofs) + o) = ov;                                      \
    } while (0)
    LN_STORE(v0, 0);    LN_STORE(v1, 256);
    LN_STORE(v2, 512);  LN_STORE(v3, 768);
    LN_STORE(v4, 1024); LN_STORE(v5, 1280);
    LN_STORE(v6, 1536); LN_STORE(v7, 1792);
    LN_STORE(v8, 2048); LN_STORE(v9, 2304);
#undef LN_STORE
  }
}

// ---------------------------------------------------------------------------
// Shared sync macros.
// ---------------------------------------------------------------------------
#define FENCE asm volatile("" ::: "memory")
#define BARRIER do { FENCE; __builtin_amdgcn_s_barrier(); FENCE; } while (0)
#define WAIT_VM(n) asm volatile("s_waitcnt vmcnt(" #n ")" ::: "memory")

// ---------------------------------------------------------------------------
// K4a: 256x256 MFMA GEMM, 4-PHASE counted-vmcnt schedule (round 11).
//
// The round-1 race happened because stage halves were M/N-contiguous while
// wave reads interleave across them.  Fix: PERMUTED LDS row order so stage
// half h contains exactly the rows ALL waves read in compute-quadrant h:
//   A half h (16KB): global rows {h*64..h*64+63} u {128+h*64..+63}
//     LDS row rr = (i*16+l15) + wm*64, read arow=(wm*64+l15)*128+ih*16384
//   B half h (16KB): global rows with bit5==h
//     LDS row rr = (j*16+l15) + wn*32, read brow=(wn*32+l15)*128+jh*16384
// Stage issue order UNIFORM across waves: SA0, SB0, SB1, SA1 (2 loads each).
//
// Per-tile ledger (per thread; all threads issue identical sequences, so a
// per-wave counted wait + s_barrier guarantees a half is fully in LDS):
//   steady 8 outstanding [SA0,SB0,SB1,SA1 of tile c]:
//   P1: vmcnt(4) retires SA0c,SB0c -> barrier -> read A0,B0 -> +SA0d (6)
//       -> MMA quad(0,0)
//   P2: vmcnt(4) retires SB1c (6->..) -> barrier -> read B1 -> +SB0d (6)
//       -> MMA quad(0,1)
//   P3: vmcnt(4) retires SA1c -> barrier -> read A1 -> +SB1d (6)
//       -> MMA quad(1,1)
//   P4: +SA1d (8) -> MMA quad(1,0) -> barrier (WAR; ds_reads all consumed
//       by prior MMAs so lgkm-drained before the barrier)
// Invariant restored; vmcnt never 0 in the loop; 16 MFMA/phase (m201
// granularity).  Epilogue drains 4->2->0.
// blockIdx.x = M-panel (same-A siblings strided 128 = same XCD, T1).
// ---------------------------------------------------------------------------
template <int KD, int LDC>
__launch_bounds__(512, 2)
__global__ void gemm256p4_kernel(const bf16_t* __restrict__ A,
                                 const bf16_t* __restrict__ Bt,
                                 const int* __restrict__ nrows_p,
                                 int row_base,
                                 const float* __restrict__ bias,
                                 bf16_t* __restrict__ Cb) {
  static_assert(KD % 64 == 0 && KD / 64 >= 2, "KD");
  const int M = *nrows_p;
  const int m0 = blockIdx.x * 256;       // M-panel on x (fast axis)
  if (row_base + m0 >= M) return;
  const int n0 = blockIdx.y * 256;       // N-panel on y

  extern __shared__ char smem[];   // [2][ A 32KB | B 32KB ] = 128 KiB

  const int t = threadIdx.x;        // 0..511
  const int lane = t & 63;
  const int wv = t >> 6;            // 0..7
  const int wm = wv >> 2;           // 0..1  (M half)
  const int wn = wv & 3;            // 0..3  (N quarter)
  const int l15 = lane & 15;
  const int l4 = lane >> 4;

  const int r0 = t >> 3;               // 0..63
  const int sq = (t & 7) ^ (r0 & 7);   // inverse-swizzled global chunk
  const bf16_t* Ab = A + (size_t)(m0 + r0) * KD + sq * 8;
  const bf16_t* Bb =
      Bt + (size_t)(n0 + (r0 >> 5) * 64 + (r0 & 31)) * KD + sq * 8;
  const int dst16 = t * 16;

  const int cs0 = (l4 ^ (l15 & 7)) << 4;   // ks=0 swizzled byte slot
  const int cs1 = cs0 ^ 64;                // ks=1
  const int arow = (wm * 64 + l15) * 128;  // within one A half (16KB)
  const int brow = (wn * 32 + l15) * 128;  // within one B half (16KB)

  f32x4 acc[2][2][4][2] = {};              // [ih][jh][i][j]
  bf16x8 a[4][2], bl[2][2], bh[2][2];

#define SA(dbuf, h, kofs)                                                    \
  do {                                                                       \
    char* _d = smem + (dbuf) * 65536 + (h) * 16384 + dst16;                  \
    async_ld16(Ab + (size_t)((h) * 64) * KD + (kofs), _d);                   \
    async_ld16(Ab + (size_t)((h) * 64 + 128) * KD + (kofs), _d + 8192);      \
  } while (0)
#define SB(dbuf, h, kofs)                                                    \
  do {                                                                       \
    char* _d = smem + (dbuf) * 65536 + 32768 + (h) * 16384 + dst16;          \
    async_ld16(Bb + (size_t)((h) * 32) * KD + (kofs), _d);                   \
    async_ld16(Bb + (size_t)((h) * 32 + 128) * KD + (kofs), _d + 8192);      \
  } while (0)
#define LA(cbuf, ih)                                                         \
  do {                                                                       \
    const char* _s = smem + (cbuf) * 65536 + (ih) * 16384 + arow;            \
    _Pragma("unroll") for (int _i = 0; _i < 4; ++_i) {                       \
      a[_i][0] = *(const bf16x8*)(_s + _i * 2048 + cs0);                     \
      a[_i][1] = *(const bf16x8*)(_s + _i * 2048 + cs1);                     \
    }                                                                        \
  } while (0)
#define LB(dst, cbuf, jh)                                                    \
  do {                                                                       \
    const char* _s = smem + (cbuf) * 65536 + 32768 + (jh) * 16384 + brow;    \
    _Pragma("unroll") for (int _j = 0; _j < 2; ++_j) {                       \
      dst[_j][0] = *(const bf16x8*)(_s + _j * 2048 + cs0);                   \
      dst[_j][1] = *(const bf16x8*)(_s + _j * 2048 + cs1);                   \
    }                                                                        \
  } while (0)
#define MMA(ih, jh, B)                                                       \
  do {                                                                       \
    _Pragma("unroll") for (int _i = 0; _i < 4; ++_i)                         \
    _Pragma("unroll") for (int _j = 0; _j < 2; ++_j) {                       \
      acc[ih][jh][_i][_j] = __builtin_amdgcn_mfma_f32_16x16x32_bf16(         \
          a[_i][0], B[_j][0], acc[ih][jh][_i][_j], 0, 0, 0);                 \
      acc[ih][jh][_i][_j] = __builtin_amdgcn_mfma_f32_16x16x32_bf16(         \
          a[_i][1], B[_j][1], acc[ih][jh][_i][_j], 0, 0, 0);                 \
    }                                                                        \
  } while (0)

  constexpr int NT = KD / 64;

  // prologue: stage tile 0 in the canonical order SA0, SB0, SB1, SA1
  SA(0, 0, 0);
  SB(0, 0, 0);
  SB(0, 1, 0);
  SA(0, 1, 0);

  int c = 0;
  for (int tk = 1; tk < NT; ++tk) {  // compute tile tk-1 (buf c), stage tk
    const int kn = tk * 64;
    const int d = c ^ 1;
    // P1: quadrant (0,0)
    WAIT_VM(4);      // retires SA0c, SB0c (8 -> 4)
    BARRIER;
    LA(c, 0);
    LB(bl, c, 0);
    SA(d, 0, kn);    // 4 -> 6
    __builtin_amdgcn_s_setprio(1);
    MMA(0, 0, bl);
    __builtin_amdgcn_s_setprio(0);
    // P2: quadrant (0,1)
    WAIT_VM(4);      // retires SB1c (6 -> 4)
    BARRIER;
    LB(bh, c, 1);
    SB(d, 0, kn);    // 4 -> 6
    __builtin_amdgcn_s_setprio(1);
    MMA(0, 1, bh);
    __builtin_amdgcn_s_setprio(0);
    // P3: quadrant (1,1)
    WAIT_VM(4);      // retires SA1c (6 -> 4)
    BARRIER;
    LA(c, 1);
    SB(d, 1, kn);    // 4 -> 6
    __builtin_amdgcn_s_setprio(1);
    MMA(1, 1, bh);
    __builtin_amdgcn_s_setprio(0);
    // P4: quadrant (1,0) — bl still in regs
    SA(d, 1, kn);    // 6 -> 8: invariant [SA0,SB0,SB1,SA1] restored
    __builtin_amdgcn_s_setprio(1);
    MMA(1, 0, bl);
    __builtin_amdgcn_s_setprio(0);
    BARRIER;         // WAR: all reads of buf c consumed (lgkm drained by
                     // the MMAs above) before next iter writes buf c
    c = d;
  }

  // epilogue tile: 8 outstanding, drain 4 -> 2 -> 0
  WAIT_VM(4);
  BARRIER;
  LA(c, 0);
  LB(bl, c, 0);
  MMA(0, 0, bl);
  WAIT_VM(2);
  BARRIER;
  LB(bh, c, 1);
  MMA(0, 1, bh);
  WAIT_VM(0);
  BARRIER;
  LA(c, 1);
  MMA(1, 1, bh);
  MMA(1, 0, bl);

  // epilogue: bias + SiLU -> bf16 (rows beyond M are garbage; GEMM2 guards)
#pragma unroll
  for (int ih = 0; ih < 2; ++ih)
#pragma unroll
    for (int i = 0; i < 4; ++i) {
      const int rbase = m0 + wm * 128 + ih * 64 + i * 16 + l4 * 4;
#pragma unroll
      for (int jh = 0; jh < 2; ++jh)
#pragma unroll
        for (int j = 0; j < 2; ++j) {
          const int n = n0 + wn * 64 + jh * 32 + j * 16 + l15;
          const float bn = bias[n];
#pragma unroll
          for (int q = 0; q < 4; ++q) {
            float v = acc[ih][jh][i][j][q] + bn;
            v = v / (1.f + __expf(-v));              // SiLU
            Cb[(size_t)(rbase + q) * LDC + n] = (bf16_t)v;
          }
        }
    }
#undef SA
#undef SB
#undef LA
#undef LB
#undef MMA
}

// ---------------------------------------------------------------------------
// K4b: 128x128 MFMA GEMM for GEMM2 (N=512), v4 counted-vmcnt ledger,
// 2 blocks/CU via __launch_bounds__(512,4).  (verified r10)
// ---------------------------------------------------------------------------
template <int KD>
__launch_bounds__(512, 4)
__global__ void gemm128_scatter_kernel(const bf16_t* __restrict__ A,
                                       const bf16_t* __restrict__ Bt,
                                       const int* __restrict__ nrows_p,
                                       int row_base,
                                       const float* __restrict__ bias,
                                       const int* __restrict__ row_dst,
                                       const float* __restrict__ pos_emb,
                                       const float* __restrict__ seq_emb,
                                       float* __restrict__ out) {
  static_assert(KD % 64 == 0 && KD / 64 >= 2, "KD");
  const int M = *nrows_p;
  const int m0 = blockIdx.x * 128;       // M-panel on x (fast axis)
  if (row_base + m0 >= M) return;
  const int n0 = blockIdx.y * 128;       // N-panel on y

  extern __shared__ char smem[];   // [2][ A 16KB | B 16KB ] = 64 KiB

  const int t = threadIdx.x;        // 0..511
  const int lane = t & 63;
  const int wv = t >> 6;            // 0..7
  const int wm = wv >> 1;           // 0..3  (M quarter, 32 rows)
  const int wn = wv & 1;            // 0..1  (N half, 64 cols)
  const int l15 = lane & 15;
  const int l4 = lane >> 4;

  const int r0 = t >> 3;               // 0..63
  const int sq = (t & 7) ^ (r0 & 7);
  const bf16_t* Ab = A + (size_t)(m0 + r0) * KD + sq * 8;
  const bf16_t* Bb = Bt + (size_t)(n0 + r0) * KD + sq * 8;
  const int dst16 = t * 16;

  const int cs0 = (l4 ^ (l15 & 7)) << 4;   // ks=0 swizzled byte slot
  const int cs1 = cs0 ^ 64;                // ks=1
  const int arow = (wm * 32 + l15) * 128;  // A row byte base for this wave
  const int brow = (wn * 64 + l15) * 128;  // B row byte base

  f32x4 acc[2][4] = {};                    // [i (16-row frag)][j (16-col frag)]
  bf16x8 a[2][2], b[4][2];

#define STAGE_A2(dbuf, kofs)                                                 \
  do {                                                                       \
    char* _d = smem + (dbuf) * 32768 + dst16;                                \
    async_ld16(Ab + (kofs), _d);                                             \
    async_ld16(Ab + (size_t)64 * KD + (kofs), _d + 8192);                    \
  } while (0)
#define STAGE_B2(dbuf, kofs)                                                 \
  do {                                                                       \
    char* _d = smem + (dbuf) * 32768 + 16384 + dst16;                        \
    async_ld16(Bb + (kofs), _d);                                             \
    async_ld16(Bb + (size_t)64 * KD + (kofs), _d + 8192);                    \
  } while (0)
#define LOAD_A2(cbuf)                                                        \
  do {                                                                       \
    const char* _s = smem + (cbuf) * 32768 + arow;                           \
    _Pragma("unroll") for (int _i = 0; _i < 2; ++_i) {                       \
      a[_i][0] = *(const bf16x8*)(_s + _i * 2048 + cs0);                     \
      a[_i][1] = *(const bf16x8*)(_s + _i * 2048 + cs1);                     \
    }                                                                        \
  } while (0)
#define LOAD_B2(cbuf)                                                        \
  do {                                                                       \
    const char* _s = smem + (cbuf) * 32768 + 16384 + brow;                   \
    _Pragma("unroll") for (int _j = 0; _j < 4; ++_j) {                       \
      b[_j][0] = *(const bf16x8*)(_s + _j * 2048 + cs0);                     \
      b[_j][1] = *(const bf16x8*)(_s + _j * 2048 + cs1);                     \
    }                                                                        \
  } while (0)
#define MMA2                                                                 \
  do {                                                                       \
    _Pragma("unroll") for (int _i = 0; _i < 2; ++_i)                         \
    _Pragma("unroll") for (int _j = 0; _j < 4; ++_j) {                       \
      acc[_i][_j] = __builtin_amdgcn_mfma_f32_16x16x32_bf16(                 \
          a[_i][0], b[_j][0], acc[_i][_j], 0, 0, 0);                         \
      acc[_i][_j] = __builtin_amdgcn_mfma_f32_16x16x32_bf16(                 \
          a[_i][1], b[_j][1], acc[_i][_j], 0, 0, 0);                         \
    }                                                                        \
  } while (0)

  constexpr int NT = KD / 64;

  // prologue: stage tile 0 (4 loads)
  STAGE_A2(0, 0);
  STAGE_B2(0, 0);

  int c = 0;
  for (int tk = 1; tk < NT; ++tk) {
    const int kn = tk * 64;
    const int d = c ^ 1;
    STAGE_A2(d, kn);            // outstanding 4 -> 6
    WAIT_VM(2);                 // retire exactly the previous tile's 4 loads
    BARRIER;
    LOAD_A2(c);
    LOAD_B2(c);
    STAGE_B2(d, kn);            // issue B after the wait: 2 -> 4
    __builtin_amdgcn_s_setprio(1);
    MMA2;
    __builtin_amdgcn_s_setprio(0);
    BARRIER;                    // WAR before next iter writes buf c
    c = d;
  }

  WAIT_VM(0);
  BARRIER;
  LOAD_A2(c);
  LOAD_B2(c);
  MMA2;

  // epilogue: scatter rows via row_dst, +bias +pos_emb +seq_emb (f32 out)
#pragma unroll
  for (int i = 0; i < 2; ++i) {
    int mbase = m0 + wm * 32 + i * 16 + l4 * 4;     // local row
#pragma unroll
    for (int q = 0; q < 4; ++q) {
      int r = mbase + q;                            // local row
      if (row_base + r >= M) continue;
      int dst = row_dst[row_base + r];              // (b*S+s)*L + slot
      int slot = dst & (NL - 1);
      int sg = (dst >> 8) & 3;
#pragma unroll
      for (int j = 0; j < 4; ++j) {
        int n = n0 + wn * 64 + j * 16 + l15;
        float v = acc[i][j][q] + bias[n] + pos_emb[slot * ND + n] +
                  seq_emb[(sg + 1) * ND + n];
        out[(size_t)dst * ND + n] = v;              // f32 output
      }
    }
  }
#undef STAGE_A2
#undef STAGE_B2
#undef LOAD_A2
#undef LOAD_B2
#undef MMA2
}

// ---------------------------------------------------------------------------
extern "C" void kernel_launch(void* const* d_in, const int* in_sizes, int n_in,
                              void* d_out, int out_size, void* d_ws,
                              size_t ws_size, hipStream_t stream) {
  const float* embed_table = (const float*)d_in[0];
  const float* time_gap_emb = (const float*)d_in[1];
  const float* seq_id_emb = (const float*)d_in[2];
  const float* pos_emb = (const float*)d_in[3];
  const float* ln_gamma = (const float*)d_in[4];
  const float* ln_beta = (const float*)d_in[5];
  const float* w1 = (const float*)d_in[6];
  const float* b1 = (const float*)d_in[7];
  const float* w2 = (const float*)d_in[8];
  const float* b2 = (const float*)d_in[9];
  const float* empty_tokens = (const float*)d_in[10];
  const int* history_tokens = (const int*)d_in[11];
  const int* post_tokens = (const int*)d_in[12];
  const int* author_tokens = (const int*)d_in[13];
  const int* action_tokens = (const int*)d_in[14];
  const int* time_gap = (const int*)d_in[15];
  const int* group_ids = (const int*)d_in[16];
  const int* lengths = (const int*)d_in[17];

  // Runtime-adaptive chunking.  ws_size is constant across calls/replays, so
  // this branch is identical on every invocation (graph-capture safe).
  const size_t fixed = 266240 + (size_t)(HID * FIVE_D + ND * HID) * 2;
  int chunk, nchunk;
  if (ws_size >= fixed + (size_t)32768 * 9216) { chunk = 32768; nchunk = 1; }
  else if (ws_size >= fixed + (size_t)16384 * 9216) { chunk = 16384; nchunk = 2; }
  else { chunk = 8192; nchunk = 4; }

  char* ws = (char*)d_ws;
  int* n_rows = (int*)ws;                                  // 4 B
  int* row_src = (int*)(ws + 4096);                        // 32768*4 B
  int* row_dst = (int*)(ws + 4096 + 131072);               // 32768*4 B
  bf16_t* W1T = (bf16_t*)(ws + 266240);                    // [2048][2560] bf16
  bf16_t* W2T = W1T + (size_t)HID * FIVE_D;                // [512][2048]  bf16
  bf16_t* Xc = W2T + (size_t)ND * HID;                     // [chunk][2560] bf16
  bf16_t* H1c = Xc + (size_t)chunk * FIVE_D;               // [chunk][2048] bf16

  float* out_states = (float*)d_out;                       // f32 output
  float* out_mask = out_states + (size_t)NB * NS * NL * ND;

  // Dynamic-LDS opt-in (host-side, idempotent, unconditional).
  (void)hipFuncSetAttribute(
      reinterpret_cast<const void*>(gemm256p4_kernel<FIVE_D, HID>),
      hipFuncAttributeMaxDynamicSharedMemorySize, 131072);
  (void)hipFuncSetAttribute(
      reinterpret_cast<const void*>(gemm128_scatter_kernel<HID>),
      hipFuncAttributeMaxDynamicSharedMemorySize, 65536);

  // n_rows must start at 0 (ws is poisoned 0xAA before every launch).
  hipMemsetAsync(n_rows, 0, 4, stream);

  build_index_kernel<<<NB * NS * 4, 256, 0, stream>>>(
      group_ids, lengths, n_rows, row_src, row_dst, empty_tokens, pos_emb,
      seq_id_emb, out_states, out_mask);

  transpose_cvt_kernel<FIVE_D, HID>
      <<<dim3(HID / 32, FIVE_D / 32), 256, 0, stream>>>(w1, W1T);
  transpose_cvt_kernel<HID, ND>
      <<<dim3(ND / 32, HID / 32), 256, 0, stream>>>(w2, W2T);

  for (int c = 0; c < nchunk; ++c) {
    int row_base = c * chunk;
    gather_ln_kernel<<<2048, 256, 0, stream>>>(
        embed_table, time_gap_emb, history_tokens, post_tokens, author_tokens,
        action_tokens, time_gap, ln_gamma, ln_beta, n_rows, row_src, row_base,
        chunk, Xc);

    gemm256p4_kernel<FIVE_D, HID>
        <<<dim3(chunk / 256, HID / 256), 512, 131072, stream>>>(
            Xc, W1T, n_rows, row_base, b1, H1c);

    gemm128_scatter_kernel<HID>
        <<<dim3(chunk / 128, ND / 128), 512, 65536, stream>>>(
            H1c, W2T, n_rows, row_base, b2, row_dst, pos_emb, seq_id_emb,
            out_states);
  }
}